// Round 1
// baseline (444.154 us; speedup 1.0000x reference)
//
#include <hip/hip_runtime.h>
#include <stdint.h>

// ---------- types ----------
typedef __attribute__((ext_vector_type(8))) __bf16 bf16x8;
typedef __attribute__((ext_vector_type(4))) float f32x4;

#define LOG2E 1.4426950408889634f

static __device__ __forceinline__ unsigned short f2bf(float x) {
  union { float f; unsigned u; } v; v.f = x;
  unsigned u = v.u;
  u += 0x7fffu + ((u >> 16) & 1u);   // RNE
  return (unsigned short)(u >> 16);
}

static __device__ __forceinline__ void async16(const void* g, void* l) {
  __builtin_amdgcn_global_load_lds(
      (const __attribute__((address_space(1))) void*)g,
      (__attribute__((address_space(3))) void*)l, 16, 0, 0);
}

// ---------- 1) hidden fp32 -> bf16 ----------
__global__ __launch_bounds__(256) void k_cvt(const float* __restrict__ x,
                                             unsigned short* __restrict__ y, int n4) {
  int i = blockIdx.x * 256 + threadIdx.x;
  if (i >= n4) return;
  float4 v = ((const float4*)x)[i];
  ushort4 o;
  o.x = f2bf(v.x); o.y = f2bf(v.y); o.z = f2bf(v.z); o.w = f2bf(v.w);
  ((ushort4*)y)[i] = o;
}

// ---------- 2) weight transpose fp32[K][N] -> bf16[N][K], scale folded for Wq ----------
__global__ __launch_bounds__(256) void k_twt(const float* __restrict__ Wq,
                                             const float* __restrict__ Wk,
                                             const float* __restrict__ Wv,
                                             const float* __restrict__ Wo,
                                             unsigned short* __restrict__ wt_qkv,
                                             unsigned short* __restrict__ wot) {
  __shared__ float tile[64][65];
  const int mat = blockIdx.z;
  const float* W = (mat == 0) ? Wq : (mat == 1) ? Wk : (mat == 2) ? Wv : Wo;
  const float scale = (mat == 0) ? 0.125f : 1.0f;   // DIM_HEAD^-0.5 folded into Wq (exact)
  const int k0 = blockIdx.y * 64, n0 = blockIdx.x * 64;
  const int t = threadIdx.x, c = t & 63;
#pragma unroll
  for (int j = 0; j < 16; ++j) {
    int r = j * 4 + (t >> 6);
    tile[r][c] = W[(size_t)(k0 + r) * 1024 + n0 + c] * scale;
  }
  __syncthreads();
  unsigned short* dst = (mat < 3) ? (wt_qkv + (size_t)mat * 1024 * 1024) : wot;
#pragma unroll
  for (int j = 0; j < 16; ++j) {
    int nr = j * 4 + (t >> 6);
    dst[(size_t)(n0 + nr) * 1024 + k0 + c] = f2bf(tile[c][nr]);
  }
}

// ---------- 3) QKV GEMM: [8192x1024]bf16 @ Bt[3072x1024]bf16 ----------
// 128x128 tile, BK=32, 4 waves in 2x2, 16x16x32 MFMA, global_load_lds staging.
__global__ __launch_bounds__(256) void k_gemm_qkv(const unsigned short* __restrict__ A,
                                                  const unsigned short* __restrict__ Bt,
                                                  unsigned short* __restrict__ q_lin,
                                                  unsigned short* __restrict__ k_lin,
                                                  unsigned short* __restrict__ vT) {
  __shared__ __align__(16) unsigned short aT[128 * 32];
  __shared__ __align__(16) unsigned short bT[128 * 32];
  const int tid = threadIdx.x, lane = tid & 63, w = tid >> 6;
  const int wr = w >> 1, wc = w & 1;
  const int m0 = blockIdx.y * 128, n0 = blockIdx.x * 128;
  const char* Ab = (const char*)A;
  const char* Bb = (const char*)Bt;
  char* aTb = (char*)aT; char* bTb = (char*)bT;
  f32x4 acc[4][4] = {};

  for (int kt = 0; kt < 32; ++kt) {
#pragma unroll
    for (int j = 0; j < 2; ++j) {
      const int ci = w * 2 + j;
      const int bo = ci * 1024 + lane * 16;
      const int row = bo >> 6, colb = bo & 63;
      async16(Ab + ((size_t)(m0 + row) * 1024 + kt * 32) * 2 + colb, aTb + ci * 1024);
      async16(Bb + ((size_t)(n0 + row) * 1024 + kt * 32) * 2 + colb, bTb + ci * 1024);
    }
    __syncthreads();
    bf16x8 af[4], bfr[4];
#pragma unroll
    for (int mi = 0; mi < 4; ++mi)
      af[mi] = *(const bf16x8*)(aTb + ((wr * 64 + mi * 16 + (lane & 15)) * 32 + (lane >> 4) * 8) * 2);
#pragma unroll
    for (int ni = 0; ni < 4; ++ni)
      bfr[ni] = *(const bf16x8*)(bTb + ((wc * 64 + ni * 16 + (lane & 15)) * 32 + (lane >> 4) * 8) * 2);
#pragma unroll
    for (int mi = 0; mi < 4; ++mi)
#pragma unroll
      for (int ni = 0; ni < 4; ++ni)
        acc[mi][ni] = __builtin_amdgcn_mfma_f32_16x16x32_bf16(af[mi], bfr[ni], acc[mi][ni], 0, 0, 0);
    __syncthreads();
  }

  const int mat = n0 >> 10;      // 0:q 1:k 2:v  (BN=128 divides 1024)
  const int nn0 = n0 & 1023;
  if (mat < 2) {
    unsigned short* dst = (mat == 0) ? q_lin : k_lin;
#pragma unroll
    for (int mi = 0; mi < 4; ++mi) {
      const int r0 = m0 + wr * 64 + mi * 16 + (lane >> 4) * 4;
#pragma unroll
      for (int ni = 0; ni < 4; ++ni) {
        const int c = nn0 + wc * 64 + ni * 16 + (lane & 15);
#pragma unroll
        for (int r = 0; r < 4; ++r)
          dst[(size_t)(r0 + r) * 1024 + c] = f2bf(acc[mi][ni][r]);
      }
    }
  } else {
    // v: store transposed vT[b][h][d][t]; 4 consecutive t per lane -> 8B store
#pragma unroll
    for (int mi = 0; mi < 4; ++mi) {
      const int r0 = m0 + wr * 64 + mi * 16 + (lane >> 4) * 4;
      const int b = r0 >> 11, tt = r0 & 2047;
#pragma unroll
      for (int ni = 0; ni < 4; ++ni) {
        const int c = nn0 + wc * 64 + ni * 16 + (lane & 15);
        const int h = c >> 6, d = c & 63;
        ushort4 o;
        o.x = f2bf(acc[mi][ni][0]); o.y = f2bf(acc[mi][ni][1]);
        o.z = f2bf(acc[mi][ni][2]); o.w = f2bf(acc[mi][ni][3]);
        *(ushort4*)(vT + ((size_t)((b * 16 + h) * 64 + d) << 11) + tt) = o;
      }
    }
  }
}

// ---------- 4) flash attention ----------
// grid (16 t-tiles, 64 bh); 4 waves; 32 q-rows/wave; KVBLK=64.
__global__ __launch_bounds__(256) void k_attn(const unsigned short* __restrict__ q_lin,
                                              const unsigned short* __restrict__ k_lin,
                                              const unsigned short* __restrict__ vT,
                                              const int* __restrict__ mask,
                                              unsigned short* __restrict__ o_lin) {
  __shared__ __align__(16) unsigned short Kt[64 * 64];   // [key][d], XOR-swizzled
  __shared__ __align__(16) unsigned short Vt[64 * 64];   // [d][j],  XOR-swizzled
  __shared__ __align__(16) unsigned short Pl[4][32 * 64];// per-wave P, swizzled
  __shared__ float biasl[64];
  const int tid = threadIdx.x, lane = tid & 63, w = tid >> 6;
  const int bh = blockIdx.y, b = bh >> 4, h = bh & 15;
  const int t0 = blockIdx.x * 128;
  const char* qbp = (const char*)(q_lin + (size_t)b * 2048 * 1024 + h * 64);
  const char* kbp = (const char*)(k_lin + (size_t)b * 2048 * 1024 + h * 64);
  const char* vbp = (const char*)(vT + ((size_t)bh * 64 << 11));
  unsigned short* obp = o_lin + (size_t)b * 2048 * 1024 + h * 64;
  const int* mp = mask + b * 2048;
  char* KtB = (char*)Kt; char* VtB = (char*)Vt;
  char* PlB = (char*)(&Pl[w][0]);

  // Q fragments held in registers the whole kernel (scale already folded into Wq)
  bf16x8 qf[2][2];
#pragma unroll
  for (int qb = 0; qb < 2; ++qb)
#pragma unroll
    for (int dc = 0; dc < 2; ++dc)
      qf[qb][dc] = *(const bf16x8*)(qbp +
          ((size_t)(t0 + w * 32 + qb * 16 + (lane & 15)) * 1024 + dc * 32 + (lane >> 4) * 8) * 2);

  f32x4 oacc[2][4] = {};
  float m_[2][4], l_[2][4];
#pragma unroll
  for (int qb = 0; qb < 2; ++qb)
#pragma unroll
    for (int r = 0; r < 4; ++r) { m_[qb][r] = -3.0e38f; l_[qb][r] = 0.f; }

  for (int kt = 0; kt < 32; ++kt) {
    const int kv0 = kt * 64;
#pragma unroll
    for (int j = 0; j < 2; ++j) {
      const int ci = w * 2 + j;
      const int bo = ci * 1024 + lane * 16;
      const int row = bo >> 7;
      const int colb = (bo & 127) ^ ((row & 7) << 4);   // pre-swizzled source (both-sides rule)
      async16(kbp + (size_t)(kv0 + row) * 2048 + colb, KtB + ci * 1024);
      async16(vbp + (size_t)row * 4096 + (size_t)kv0 * 2 + colb, VtB + ci * 1024);
    }
    if (tid < 64) biasl[tid] = (mp[kv0 + tid] == 0) ? -__builtin_inff() : 0.0f;
    __syncthreads();

    bf16x8 kf[4][2], vf[4][2];
#pragma unroll
    for (int kb = 0; kb < 4; ++kb)
#pragma unroll
      for (int dc = 0; dc < 2; ++dc) {
        const int row = kb * 16 + (lane & 15);
        kf[kb][dc] = *(const bf16x8*)(KtB + row * 128 + ((dc * 64 + (lane >> 4) * 16) ^ ((row & 7) << 4)));
      }
#pragma unroll
    for (int db = 0; db < 4; ++db)
#pragma unroll
      for (int jc = 0; jc < 2; ++jc) {
        const int row = db * 16 + (lane & 15);
        vf[db][jc] = *(const bf16x8*)(VtB + row * 128 + ((jc * 64 + (lane >> 4) * 16) ^ ((row & 7) << 4)));
      }
    float bb[4];
#pragma unroll
    for (int kb = 0; kb < 4; ++kb) bb[kb] = biasl[kb * 16 + (lane & 15)];

#pragma unroll
    for (int qb = 0; qb < 2; ++qb) {
      // S = Q K^T (+ mask bias)
      f32x4 s[4];
#pragma unroll
      for (int kb = 0; kb < 4; ++kb) {
        f32x4 sc = {};
        sc = __builtin_amdgcn_mfma_f32_16x16x32_bf16(qf[qb][0], kf[kb][0], sc, 0, 0, 0);
        sc = __builtin_amdgcn_mfma_f32_16x16x32_bf16(qf[qb][1], kf[kb][1], sc, 0, 0, 0);
#pragma unroll
        for (int r = 0; r < 4; ++r) sc[r] += bb[kb];
        s[kb] = sc;
      }
      // online softmax (rows live in 16-lane groups)
      float mt[4];
#pragma unroll
      for (int r = 0; r < 4; ++r)
        mt[r] = fmaxf(fmaxf(s[0][r], s[1][r]), fmaxf(s[2][r], s[3][r]));
#pragma unroll
      for (int off = 1; off < 16; off <<= 1)
#pragma unroll
        for (int r = 0; r < 4; ++r) mt[r] = fmaxf(mt[r], __shfl_xor(mt[r], off));
      float mn[4], sf[4];
#pragma unroll
      for (int r = 0; r < 4; ++r) {
        mn[r] = fmaxf(m_[qb][r], mt[r]);          // finite (init -3e38) => no NaN vs -inf bias
        sf[r] = exp2f((m_[qb][r] - mn[r]) * LOG2E);
        m_[qb][r] = mn[r];
      }
      float pr[4][4], rs[4] = {0.f, 0.f, 0.f, 0.f};
#pragma unroll
      for (int kb = 0; kb < 4; ++kb)
#pragma unroll
        for (int r = 0; r < 4; ++r) {
          float p = exp2f((s[kb][r] - mn[r]) * LOG2E);
          pr[kb][r] = p;
          rs[r] += p;
        }
#pragma unroll
      for (int off = 1; off < 16; off <<= 1)
#pragma unroll
        for (int r = 0; r < 4; ++r) rs[r] += __shfl_xor(rs[r], off);
#pragma unroll
      for (int r = 0; r < 4; ++r) l_[qb][r] = l_[qb][r] * sf[r] + rs[r];
#pragma unroll
      for (int db = 0; db < 4; ++db)
#pragma unroll
        for (int r = 0; r < 4; ++r) oacc[qb][db][r] *= sf[r];
      // P -> per-wave LDS (swizzled), then back as A-fragments
#pragma unroll
      for (int kb = 0; kb < 4; ++kb)
#pragma unroll
        for (int r = 0; r < 4; ++r) {
          const int prow = qb * 16 + (lane >> 4) * 4 + r;
          const int pcolb = (kb * 16 + (lane & 15)) * 2;
          *(unsigned short*)(PlB + prow * 128 + (pcolb ^ ((prow & 7) << 4))) = f2bf(pr[kb][r]);
        }
      bf16x8 pa[2];
#pragma unroll
      for (int jc = 0; jc < 2; ++jc) {
        const int prow = qb * 16 + (lane & 15);
        pa[jc] = *(const bf16x8*)(PlB + prow * 128 + ((jc * 64 + (lane >> 4) * 16) ^ ((prow & 7) << 4)));
      }
#pragma unroll
      for (int db = 0; db < 4; ++db) {
        oacc[qb][db] = __builtin_amdgcn_mfma_f32_16x16x32_bf16(pa[0], vf[db][0], oacc[qb][db], 0, 0, 0);
        oacc[qb][db] = __builtin_amdgcn_mfma_f32_16x16x32_bf16(pa[1], vf[db][1], oacc[qb][db], 0, 0, 0);
      }
    }
    __syncthreads();
  }
  // epilogue: O /= l, store bf16
#pragma unroll
  for (int qb = 0; qb < 2; ++qb)
#pragma unroll
    for (int r = 0; r < 4; ++r) {
      const float inv = 1.0f / l_[qb][r];
      const int row = t0 + w * 32 + qb * 16 + (lane >> 4) * 4 + r;
#pragma unroll
      for (int db = 0; db < 4; ++db)
        obp[(size_t)row * 1024 + db * 16 + (lane & 15)] = f2bf(oacc[qb][db][r] * inv);
    }
}

// ---------- 5) output GEMM + bias -> fp32 ----------
__global__ __launch_bounds__(256) void k_gemm_out(const unsigned short* __restrict__ A,
                                                  const unsigned short* __restrict__ Bt,
                                                  const float* __restrict__ bias,
                                                  float* __restrict__ out) {
  __shared__ __align__(16) unsigned short aT[128 * 32];
  __shared__ __align__(16) unsigned short bT[128 * 32];
  const int tid = threadIdx.x, lane = tid & 63, w = tid >> 6;
  const int wr = w >> 1, wc = w & 1;
  const int m0 = blockIdx.y * 128, n0 = blockIdx.x * 128;
  const char* Ab = (const char*)A;
  const char* Bb = (const char*)Bt;
  char* aTb = (char*)aT; char* bTb = (char*)bT;
  f32x4 acc[4][4] = {};

  for (int kt = 0; kt < 32; ++kt) {
#pragma unroll
    for (int j = 0; j < 2; ++j) {
      const int ci = w * 2 + j;
      const int bo = ci * 1024 + lane * 16;
      const int row = bo >> 6, colb = bo & 63;
      async16(Ab + ((size_t)(m0 + row) * 1024 + kt * 32) * 2 + colb, aTb + ci * 1024);
      async16(Bb + ((size_t)(n0 + row) * 1024 + kt * 32) * 2 + colb, bTb + ci * 1024);
    }
    __syncthreads();
    bf16x8 af[4], bfr[4];
#pragma unroll
    for (int mi = 0; mi < 4; ++mi)
      af[mi] = *(const bf16x8*)(aTb + ((wr * 64 + mi * 16 + (lane & 15)) * 32 + (lane >> 4) * 8) * 2);
#pragma unroll
    for (int ni = 0; ni < 4; ++ni)
      bfr[ni] = *(const bf16x8*)(bTb + ((wc * 64 + ni * 16 + (lane & 15)) * 32 + (lane >> 4) * 8) * 2);
#pragma unroll
    for (int mi = 0; mi < 4; ++mi)
#pragma unroll
      for (int ni = 0; ni < 4; ++ni)
        acc[mi][ni] = __builtin_amdgcn_mfma_f32_16x16x32_bf16(af[mi], bfr[ni], acc[mi][ni], 0, 0, 0);
    __syncthreads();
  }
#pragma unroll
  for (int mi = 0; mi < 4; ++mi) {
    const int r0 = m0 + wr * 64 + mi * 16 + (lane >> 4) * 4;
#pragma unroll
    for (int ni = 0; ni < 4; ++ni) {
      const int c = n0 + wc * 64 + ni * 16 + (lane & 15);
      const float bb = bias[c];
#pragma unroll
      for (int r = 0; r < 4; ++r)
        out[(size_t)(r0 + r) * 1024 + c] = acc[mi][ni][r] + bb;
    }
  }
}

// ---------- launcher ----------
extern "C" void kernel_launch(void* const* d_in, const int* in_sizes, int n_in,
                              void* d_out, int out_size, void* d_ws, size_t ws_size,
                              hipStream_t stream) {
  const float* hs   = (const float*)d_in[0];
  const int*   mask = (const int*)d_in[1];
  const float* Wq   = (const float*)d_in[2];
  const float* Wk   = (const float*)d_in[3];
  const float* Wv   = (const float*)d_in[4];
  const float* Wo   = (const float*)d_in[5];
  const float* bo   = (const float*)d_in[6];
  float* out = (float*)d_out;

  const size_t MB = 1024 * 1024;
  char* ws = (char*)d_ws;
  unsigned short* hs_bf  = (unsigned short*)(ws);             // 16 MB  [8192][1024]
  unsigned short* wt_qkv = (unsigned short*)(ws + 16 * MB);   //  6 MB  [3072][1024] (q scaled)
  unsigned short* wot    = (unsigned short*)(ws + 22 * MB);   //  2 MB  [1024][1024]
  unsigned short* q_lin  = (unsigned short*)(ws + 24 * MB);   // 16 MB  [8192][1024]
  unsigned short* k_lin  = (unsigned short*)(ws + 40 * MB);   // 16 MB  [8192][1024]
  unsigned short* vT     = (unsigned short*)(ws + 56 * MB);   // 16 MB  [4][16][64][2048]
  unsigned short* o_lin  = (unsigned short*)(ws + 72 * MB);   // 16 MB  [8192][1024]

  k_cvt<<<8192, 256, 0, stream>>>(hs, hs_bf, 2097152);
  k_twt<<<dim3(16, 16, 4), 256, 0, stream>>>(Wq, Wk, Wv, Wo, wt_qkv, wot);
  k_gemm_qkv<<<dim3(24, 64), 256, 0, stream>>>(hs_bf, wt_qkv, q_lin, k_lin, vT);
  k_attn<<<dim3(16, 64), 256, 0, stream>>>(q_lin, k_lin, vT, mask, o_lin);
  k_gemm_out<<<dim3(8, 64), 256, 0, stream>>>(o_lin, wot, bo, out);
}

// Round 2
// 352.246 us; speedup vs baseline: 1.2609x; 1.2609x over previous
//
#include <hip/hip_runtime.h>
#include <stdint.h>

// ---------- types ----------
typedef __attribute__((ext_vector_type(8))) __bf16 bf16x8;
typedef __attribute__((ext_vector_type(4))) float f32x4;

#define QSCALE 0.18033688011112042f   // 0.125 * log2(e): softmax computed base-2

static __device__ __forceinline__ unsigned short f2bf(float x) {
  return __builtin_bit_cast(unsigned short, (__bf16)x);   // v_cvt_pk_bf16_f32 (RNE)
}

static __device__ __forceinline__ void async16(const void* g, void* l) {
  __builtin_amdgcn_global_load_lds(
      (const __attribute__((address_space(1))) void*)g,
      (__attribute__((address_space(3))) void*)l, 16, 0, 0);
}

// ---------- 1) hidden fp32 -> bf16 ----------
__global__ __launch_bounds__(256) void k_cvt(const float* __restrict__ x,
                                             unsigned short* __restrict__ y, int n4) {
  int i = blockIdx.x * 256 + threadIdx.x;
  if (i >= n4) return;
  float4 v = ((const float4*)x)[i];
  ushort4 o;
  o.x = f2bf(v.x); o.y = f2bf(v.y); o.z = f2bf(v.z); o.w = f2bf(v.w);
  ((ushort4*)y)[i] = o;
}

// ---------- 2) weight transpose fp32[K][N] -> bf16[N][K] ----------
__global__ __launch_bounds__(256) void k_twt(const float* __restrict__ Wq,
                                             const float* __restrict__ Wk,
                                             const float* __restrict__ Wv,
                                             const float* __restrict__ Wo,
                                             unsigned short* __restrict__ wt_qkv,
                                             unsigned short* __restrict__ wot) {
  __shared__ float tile[64][65];
  const int mat = blockIdx.z;
  const float* W = (mat == 0) ? Wq : (mat == 1) ? Wk : (mat == 2) ? Wv : Wo;
  const float scale = (mat == 0) ? QSCALE : 1.0f;   // attn scale + log2e folded into Wq
  const int k0 = blockIdx.y * 64, n0 = blockIdx.x * 64;
  const int t = threadIdx.x, c = t & 63;
#pragma unroll
  for (int j = 0; j < 16; ++j) {
    int r = j * 4 + (t >> 6);
    tile[r][c] = W[(size_t)(k0 + r) * 1024 + n0 + c] * scale;
  }
  __syncthreads();
  unsigned short* dst = (mat < 3) ? (wt_qkv + (size_t)mat * 1024 * 1024) : wot;
#pragma unroll
  for (int j = 0; j < 16; ++j) {
    int nr = j * 4 + (t >> 6);
    dst[(size_t)(n0 + nr) * 1024 + k0 + c] = f2bf(tile[c][nr]);
  }
}

// ---------- 3) QKV GEMM (2-phase double-buffered) ----------
__global__ __launch_bounds__(256) void k_gemm_qkv(const unsigned short* __restrict__ A,
                                                  const unsigned short* __restrict__ Bt,
                                                  unsigned short* __restrict__ q_lin,
                                                  unsigned short* __restrict__ k_lin,
                                                  unsigned short* __restrict__ vT) {
  __shared__ __align__(16) unsigned short aT[2][128 * 32];
  __shared__ __align__(16) unsigned short bT[2][128 * 32];
  const int tid = threadIdx.x, lane = tid & 63, w = tid >> 6;
  const int wr = w >> 1, wc = w & 1;
  const int m0 = blockIdx.y * 128, n0 = blockIdx.x * 128;
  const char* Ab = (const char*)A;
  const char* Bb = (const char*)Bt;
  char* aTb = (char*)aT; char* bTb = (char*)bT;
  f32x4 acc[4][4] = {};

  const int ci0 = w * 2, bo0 = ci0 * 1024 + lane * 16;
  const int srow0 = bo0 >> 6, scol0 = bo0 & 63;
#define G_STAGE(buf, kt)                                                              \
  {                                                                                   \
    _Pragma("unroll")                                                                 \
    for (int j = 0; j < 2; ++j) {                                                     \
      const int row = srow0 + j * 16;                                                 \
      async16(Ab + ((size_t)(m0 + row) * 1024 + (kt) * 32) * 2 + scol0,               \
              aTb + (buf) * 8192 + (ci0 + j) * 1024);                                 \
      async16(Bb + ((size_t)(n0 + row) * 1024 + (kt) * 32) * 2 + scol0,               \
              bTb + (buf) * 8192 + (ci0 + j) * 1024);                                 \
    }                                                                                 \
  }

  G_STAGE(0, 0);
  __syncthreads();
  for (int kt = 0; kt < 32; ++kt) {
    const int cur = kt & 1;
    if (kt + 1 < 32) G_STAGE(cur ^ 1, kt + 1);
    bf16x8 af[4], bfr[4];
#pragma unroll
    for (int mi = 0; mi < 4; ++mi)
      af[mi] = *(const bf16x8*)(aTb + cur * 8192 +
               ((wr * 64 + mi * 16 + (lane & 15)) * 32 + (lane >> 4) * 8) * 2);
#pragma unroll
    for (int ni = 0; ni < 4; ++ni)
      bfr[ni] = *(const bf16x8*)(bTb + cur * 8192 +
               ((wc * 64 + ni * 16 + (lane & 15)) * 32 + (lane >> 4) * 8) * 2);
#pragma unroll
    for (int mi = 0; mi < 4; ++mi)
#pragma unroll
      for (int ni = 0; ni < 4; ++ni)
        acc[mi][ni] = __builtin_amdgcn_mfma_f32_16x16x32_bf16(af[mi], bfr[ni], acc[mi][ni], 0, 0, 0);
    __syncthreads();
  }
#undef G_STAGE

  const int mat = n0 >> 10;
  const int nn0 = n0 & 1023;
  if (mat < 2) {
    unsigned short* dst = (mat == 0) ? q_lin : k_lin;
#pragma unroll
    for (int mi = 0; mi < 4; ++mi) {
      const int r0 = m0 + wr * 64 + mi * 16 + (lane >> 4) * 4;
#pragma unroll
      for (int ni = 0; ni < 4; ++ni) {
        const int c = nn0 + wc * 64 + ni * 16 + (lane & 15);
#pragma unroll
        for (int r = 0; r < 4; ++r)
          dst[(size_t)(r0 + r) * 1024 + c] = f2bf(acc[mi][ni][r]);
      }
    }
  } else {
#pragma unroll
    for (int mi = 0; mi < 4; ++mi) {
      const int r0 = m0 + wr * 64 + mi * 16 + (lane >> 4) * 4;
      const int b = r0 >> 11, tt = r0 & 2047;
#pragma unroll
      for (int ni = 0; ni < 4; ++ni) {
        const int c = nn0 + wc * 64 + ni * 16 + (lane & 15);
        const int h = c >> 6, d = c & 63;
        ushort4 o;
        o.x = f2bf(acc[mi][ni][0]); o.y = f2bf(acc[mi][ni][1]);
        o.z = f2bf(acc[mi][ni][2]); o.w = f2bf(acc[mi][ni][3]);
        *(ushort4*)(vT + ((size_t)((b * 16 + h) * 64 + d) << 11) + tt) = o;
      }
    }
  }
}

// ---------- 4) flash attention, swapped-QK^T in-lane softmax ----------
// grid (16 t-tiles, 64 bh); 4 waves; 32 q/wave (2 fragments of 16); KVBLK=64.
__global__ __launch_bounds__(256, 3) void k_attn(const unsigned short* __restrict__ q_lin,
                                                 const unsigned short* __restrict__ k_lin,
                                                 const unsigned short* __restrict__ vT,
                                                 const int* __restrict__ mask,
                                                 unsigned short* __restrict__ o_lin) {
  __shared__ __align__(16) unsigned short Kt[2][64 * 64];   // [key][d], swizzled
  __shared__ __align__(16) unsigned short Vt[2][64 * 64];   // [d][key], swizzled
  __shared__ __align__(16) unsigned short Pl[4][16 * 64];   // per-wave P[q][key], swizzled
  __shared__ __align__(16) float biasl[2][64];
  const int tid = threadIdx.x, lane = tid & 63, w = tid >> 6;
  const int qq = lane & 15, g = lane >> 4;
  const int bh = blockIdx.y, b = bh >> 4, h = bh & 15;
  const int t0 = blockIdx.x * 128;
  const char* qbp = (const char*)(q_lin + (size_t)b * 2048 * 1024 + h * 64);
  const char* kbp = (const char*)(k_lin + (size_t)b * 2048 * 1024 + h * 64);
  const char* vbp = (const char*)(vT + ((size_t)bh * 64 << 11));
  unsigned short* obp = o_lin + (size_t)b * 2048 * 1024 + h * 64;
  const int* mp = mask + b * 2048;
  char* KtB = (char*)Kt; char* VtB = (char*)Vt;
  char* PlB = (char*)(&Pl[w][0]);
  const int psw = (qq & 7) << 4;

  // Q fragments in registers (scale+log2e folded into Wq)
  bf16x8 qf[2][2];
#pragma unroll
  for (int qb = 0; qb < 2; ++qb)
#pragma unroll
    for (int dc = 0; dc < 2; ++dc)
      qf[qb][dc] = *(const bf16x8*)(qbp +
          ((size_t)(t0 + w * 32 + qb * 16 + qq) * 1024 + dc * 32 + g * 8) * 2);

  f32x4 oacc[2][4] = {};          // O^T fragments: col = own q, rows = d
  float m_[2] = {-3.0e38f, -3.0e38f}, l_[2] = {0.f, 0.f};

  const int sci = w * 2, sbo = sci * 1024 + lane * 16;
  const int srow = sbo >> 7;
  const int scolb = (sbo & 127) ^ ((srow & 7) << 4);   // pre-swizzled source
#define A_STAGE(buf, kv0)                                                             \
  {                                                                                   \
    _Pragma("unroll")                                                                 \
    for (int j = 0; j < 2; ++j) {                                                     \
      const int row = srow + j * 8;                                                   \
      async16(kbp + (size_t)((kv0) + row) * 2048 + scolb,                             \
              KtB + (buf) * 8192 + (sci + j) * 1024);                                 \
      async16(vbp + (size_t)row * 4096 + (size_t)(kv0) * 2 + scolb,                   \
              VtB + (buf) * 8192 + (sci + j) * 1024);                                 \
    }                                                                                 \
    if (tid < 64) biasl[buf][tid] = (mp[(kv0) + tid] == 0) ? -__builtin_inff() : 0.0f;\
  }

  A_STAGE(0, 0);
  __syncthreads();

  for (int kt = 0; kt < 32; ++kt) {
    const int cur = kt & 1;
    if (kt + 1 < 32) A_STAGE(cur ^ 1, (kt + 1) * 64);

    bf16x8 kf[4][2], vf[4][2];
#pragma unroll
    for (int kb = 0; kb < 4; ++kb)
#pragma unroll
      for (int dc = 0; dc < 2; ++dc) {
        const int row = kb * 16 + qq;
        kf[kb][dc] = *(const bf16x8*)(KtB + cur * 8192 + row * 128 +
                                      ((dc * 64 + g * 16) ^ ((row & 7) << 4)));
      }
#pragma unroll
    for (int db = 0; db < 4; ++db)
#pragma unroll
      for (int hc = 0; hc < 2; ++hc) {
        const int row = db * 16 + qq;
        vf[db][hc] = *(const bf16x8*)(VtB + cur * 8192 + row * 128 +
                                      ((hc * 64 + g * 16) ^ ((row & 7) << 4)));
      }
    float4 bb[4];
#pragma unroll
    for (int kb = 0; kb < 4; ++kb) bb[kb] = ((const float4*)biasl[cur])[kb * 4 + g];

#pragma unroll
    for (int qb = 0; qb < 2; ++qb) {
      // S^T = K Q^T : lane owns q = qq, keys kb*16 + g*4 + r  (log2-domain scores)
      f32x4 s[4];
#pragma unroll
      for (int kb = 0; kb < 4; ++kb) {
        f32x4 sc = {};
        sc = __builtin_amdgcn_mfma_f32_16x16x32_bf16(kf[kb][0], qf[qb][0], sc, 0, 0, 0);
        sc = __builtin_amdgcn_mfma_f32_16x16x32_bf16(kf[kb][1], qf[qb][1], sc, 0, 0, 0);
        sc[0] += bb[kb].x; sc[1] += bb[kb].y; sc[2] += bb[kb].z; sc[3] += bb[kb].w;
        s[kb] = sc;
      }
      // in-lane max over 16 keys, then 2 shuffles across the 4 key-groups
      float mx[4];
#pragma unroll
      for (int kb = 0; kb < 4; ++kb)
        mx[kb] = fmaxf(fmaxf(s[kb][0], s[kb][1]), fmaxf(s[kb][2], s[kb][3]));
      float mt = fmaxf(fmaxf(mx[0], mx[1]), fmaxf(mx[2], mx[3]));
      mt = fmaxf(mt, __shfl_xor(mt, 16));
      mt = fmaxf(mt, __shfl_xor(mt, 32));
      // defer-max (T13, THR=8 in log2 units)
      if (__any(mt > m_[qb] + 8.0f)) {
        const float mn = fmaxf(m_[qb], mt);
        const float sf = __builtin_amdgcn_exp2f(m_[qb] - mn);
        m_[qb] = mn;
        l_[qb] *= sf;
#pragma unroll
        for (int db = 0; db < 4; ++db)
#pragma unroll
          for (int r = 0; r < 4; ++r) oacc[qb][db][r] *= sf;
      }
      const float mm = m_[qb];
      float rs = 0.f;
#pragma unroll
      for (int kb = 0; kb < 4; ++kb) {
        const float e0 = __builtin_amdgcn_exp2f(s[kb][0] - mm);
        const float e1 = __builtin_amdgcn_exp2f(s[kb][1] - mm);
        const float e2 = __builtin_amdgcn_exp2f(s[kb][2] - mm);
        const float e3 = __builtin_amdgcn_exp2f(s[kb][3] - mm);
        rs += (e0 + e1) + (e2 + e3);
        ushort4 pk;
        pk.x = f2bf(e0); pk.y = f2bf(e1); pk.z = f2bf(e2); pk.w = f2bf(e3);
        *(ushort4*)(PlB + qq * 128 + ((kb * 32 + g * 8) ^ psw)) = pk;
      }
      rs += __shfl_xor(rs, 16);
      rs += __shfl_xor(rs, 32);
      l_[qb] += rs;
      // P fragments back (lane's own q, 8 keys each)
      bf16x8 pf[2];
#pragma unroll
      for (int hc = 0; hc < 2; ++hc)
        pf[hc] = *(const bf16x8*)(PlB + qq * 128 + ((hc * 64 + g * 16) ^ psw));
      // O^T += V^T P^T
#pragma unroll
      for (int db = 0; db < 4; ++db) {
        oacc[qb][db] = __builtin_amdgcn_mfma_f32_16x16x32_bf16(vf[db][0], pf[0], oacc[qb][db], 0, 0, 0);
        oacc[qb][db] = __builtin_amdgcn_mfma_f32_16x16x32_bf16(vf[db][1], pf[1], oacc[qb][db], 0, 0, 0);
      }
    }
    __syncthreads();
  }
#undef A_STAGE

  // epilogue: O^T cols are the lane's own q; rows d = db*16 + g*4 + r
#pragma unroll
  for (int qb = 0; qb < 2; ++qb) {
    const float inv = 1.0f / l_[qb];
    const int qrow = t0 + w * 32 + qb * 16 + qq;
#pragma unroll
    for (int db = 0; db < 4; ++db) {
      ushort4 o;
      o.x = f2bf(oacc[qb][db][0] * inv); o.y = f2bf(oacc[qb][db][1] * inv);
      o.z = f2bf(oacc[qb][db][2] * inv); o.w = f2bf(oacc[qb][db][3] * inv);
      *(ushort4*)(obp + (size_t)qrow * 1024 + db * 16 + g * 4) = o;
    }
  }
}

// ---------- 5) output GEMM + bias -> fp32 (2-phase double-buffered) ----------
__global__ __launch_bounds__(256) void k_gemm_out(const unsigned short* __restrict__ A,
                                                  const unsigned short* __restrict__ Bt,
                                                  const float* __restrict__ bias,
                                                  float* __restrict__ out) {
  __shared__ __align__(16) unsigned short aT[2][128 * 32];
  __shared__ __align__(16) unsigned short bT[2][128 * 32];
  const int tid = threadIdx.x, lane = tid & 63, w = tid >> 6;
  const int wr = w >> 1, wc = w & 1;
  const int m0 = blockIdx.y * 128, n0 = blockIdx.x * 128;
  const char* Ab = (const char*)A;
  const char* Bb = (const char*)Bt;
  char* aTb = (char*)aT; char* bTb = (char*)bT;
  f32x4 acc[4][4] = {};

  const int ci0 = w * 2, bo0 = ci0 * 1024 + lane * 16;
  const int srow0 = bo0 >> 6, scol0 = bo0 & 63;
#define G_STAGE(buf, kt)                                                              \
  {                                                                                   \
    _Pragma("unroll")                                                                 \
    for (int j = 0; j < 2; ++j) {                                                     \
      const int row = srow0 + j * 16;                                                 \
      async16(Ab + ((size_t)(m0 + row) * 1024 + (kt) * 32) * 2 + scol0,               \
              aTb + (buf) * 8192 + (ci0 + j) * 1024);                                 \
      async16(Bb + ((size_t)(n0 + row) * 1024 + (kt) * 32) * 2 + scol0,               \
              bTb + (buf) * 8192 + (ci0 + j) * 1024);                                 \
    }                                                                                 \
  }

  G_STAGE(0, 0);
  __syncthreads();
  for (int kt = 0; kt < 32; ++kt) {
    const int cur = kt & 1;
    if (kt + 1 < 32) G_STAGE(cur ^ 1, kt + 1);
    bf16x8 af[4], bfr[4];
#pragma unroll
    for (int mi = 0; mi < 4; ++mi)
      af[mi] = *(const bf16x8*)(aTb + cur * 8192 +
               ((wr * 64 + mi * 16 + (lane & 15)) * 32 + (lane >> 4) * 8) * 2);
#pragma unroll
    for (int ni = 0; ni < 4; ++ni)
      bfr[ni] = *(const bf16x8*)(bTb + cur * 8192 +
               ((wc * 64 + ni * 16 + (lane & 15)) * 32 + (lane >> 4) * 8) * 2);
#pragma unroll
    for (int mi = 0; mi < 4; ++mi)
#pragma unroll
      for (int ni = 0; ni < 4; ++ni)
        acc[mi][ni] = __builtin_amdgcn_mfma_f32_16x16x32_bf16(af[mi], bfr[ni], acc[mi][ni], 0, 0, 0);
    __syncthreads();
  }
#undef G_STAGE
#pragma unroll
  for (int mi = 0; mi < 4; ++mi) {
    const int r0 = m0 + wr * 64 + mi * 16 + (lane >> 4) * 4;
#pragma unroll
    for (int ni = 0; ni < 4; ++ni) {
      const int c = n0 + wc * 64 + ni * 16 + (lane & 15);
      const float bb = bias[c];
#pragma unroll
      for (int r = 0; r < 4; ++r)
        out[(size_t)(r0 + r) * 1024 + c] = acc[mi][ni][r] + bb;
    }
  }
}

// ---------- launcher ----------
extern "C" void kernel_launch(void* const* d_in, const int* in_sizes, int n_in,
                              void* d_out, int out_size, void* d_ws, size_t ws_size,
                              hipStream_t stream) {
  const float* hs   = (const float*)d_in[0];
  const int*   mask = (const int*)d_in[1];
  const float* Wq   = (const float*)d_in[2];
  const float* Wk   = (const float*)d_in[3];
  const float* Wv   = (const float*)d_in[4];
  const float* Wo   = (const float*)d_in[5];
  const float* bo   = (const float*)d_in[6];
  float* out = (float*)d_out;

  const size_t MB = 1024 * 1024;
  char* ws = (char*)d_ws;
  unsigned short* hs_bf  = (unsigned short*)(ws);             // 16 MB
  unsigned short* wt_qkv = (unsigned short*)(ws + 16 * MB);   //  6 MB (q pre-scaled)
  unsigned short* wot    = (unsigned short*)(ws + 22 * MB);   //  2 MB
  unsigned short* q_lin  = (unsigned short*)(ws + 24 * MB);   // 16 MB
  unsigned short* k_lin  = (unsigned short*)(ws + 40 * MB);   // 16 MB
  unsigned short* vT     = (unsigned short*)(ws + 56 * MB);   // 16 MB [b][h][d][t]
  unsigned short* o_lin  = (unsigned short*)(ws + 72 * MB);   // 16 MB

  k_cvt<<<8192, 256, 0, stream>>>(hs, hs_bf, 2097152);
  k_twt<<<dim3(16, 16, 4), 256, 0, stream>>>(Wq, Wk, Wv, Wo, wt_qkv, wot);
  k_gemm_qkv<<<dim3(24, 64), 256, 0, stream>>>(hs_bf, wt_qkv, q_lin, k_lin, vT);
  k_attn<<<dim3(16, 64), 256, 0, stream>>>(q_lin, k_lin, vT, mask, o_lin);
  k_gemm_out<<<dim3(8, 64), 256, 0, stream>>>(o_lin, wot, bo, out);
}

// Round 4
// 315.943 us; speedup vs baseline: 1.4058x; 1.1149x over previous
//
#include <hip/hip_runtime.h>
#include <stdint.h>

// ---------- types ----------
typedef __attribute__((ext_vector_type(8))) __bf16 bf16x8;
typedef __attribute__((ext_vector_type(4))) float f32x4;
typedef __attribute__((ext_vector_type(16))) float f32x16;

#define QSCALE 0.18033688011112042f   // 0.125 * log2(e): softmax computed base-2

static __device__ __forceinline__ unsigned short f2bf(float x) {
  return __builtin_bit_cast(unsigned short, (__bf16)x);
}
static __device__ __forceinline__ unsigned pkbf(float a, float b) {
  union { unsigned short h[2]; unsigned u; } r;
  r.h[0] = f2bf(a); r.h[1] = f2bf(b); return r.u;
}
static __device__ __forceinline__ void async16(const void* g, void* l) {
  __builtin_amdgcn_global_load_lds(
      (const __attribute__((address_space(1))) void*)g,
      (__attribute__((address_space(3))) void*)l, 16, 0, 0);
}

// ---------- 1) prep: hidden fp32->bf16 (blocks 0..8191) + weight transpose (8192..9215) ----------
__global__ __launch_bounds__(256) void k_prep(const float* __restrict__ hs,
                                              const float* __restrict__ Wq,
                                              const float* __restrict__ Wk,
                                              const float* __restrict__ Wv,
                                              const float* __restrict__ Wo,
                                              unsigned short* __restrict__ hs_bf,
                                              unsigned short* __restrict__ wt_qkv,
                                              unsigned short* __restrict__ wot) {
  __shared__ float tile[64][65];
  const int bid = blockIdx.x;
  if (bid < 8192) {
    const int i = bid * 256 + threadIdx.x;
    float4 v = ((const float4*)hs)[i];
    ushort4 o;
    o.x = f2bf(v.x); o.y = f2bf(v.y); o.z = f2bf(v.z); o.w = f2bf(v.w);
    ((ushort4*)hs_bf)[i] = o;
    return;
  }
  const int idx = bid - 8192;
  const int mat = idx >> 8;
  const float* W = (mat == 0) ? Wq : (mat == 1) ? Wk : (mat == 2) ? Wv : Wo;
  const float scale = (mat == 0) ? QSCALE : 1.0f;   // attn scale + log2e folded into Wq
  const int n0 = (idx & 15) * 64, k0 = ((idx >> 4) & 15) * 64;
  const int t = threadIdx.x, c = t & 63;
#pragma unroll
  for (int j = 0; j < 16; ++j) {
    int r = j * 4 + (t >> 6);
    tile[r][c] = W[(size_t)(k0 + r) * 1024 + n0 + c] * scale;
  }
  __syncthreads();
  unsigned short* dst = (mat < 3) ? (wt_qkv + (size_t)mat * 1024 * 1024) : wot;
#pragma unroll
  for (int j = 0; j < 16; ++j) {
    int nr = j * 4 + (t >> 6);
    dst[(size_t)(n0 + nr) * 1024 + k0 + c] = f2bf(tile[c][nr]);
  }
}

// ---------- 2) QKV GEMM (2-phase dbuf, XCD-swizzled) ----------
__global__ __launch_bounds__(256) void k_gemm_qkv(const unsigned short* __restrict__ A,
                                                  const unsigned short* __restrict__ Bt,
                                                  unsigned short* __restrict__ q_lin,
                                                  unsigned short* __restrict__ k_lin,
                                                  unsigned short* __restrict__ vT) {
  __shared__ __align__(16) unsigned short aT[2][128 * 32];
  __shared__ __align__(16) unsigned short bT[2][128 * 32];
  const int tid = threadIdx.x, lane = tid & 63, w = tid >> 6;
  const int wr = w >> 1, wc = w & 1;
  // bijective XCD swizzle (nwg = 24*64 = 1536, %8==0)
  int flat = blockIdx.y * 24 + blockIdx.x;
  flat = (flat & 7) * 192 + (flat >> 3);
  const int m0 = (flat / 24) * 128, n0 = (flat % 24) * 128;
  const char* Ab = (const char*)A;
  const char* Bb = (const char*)Bt;
  char* aTb = (char*)aT; char* bTb = (char*)bT;
  f32x4 acc[4][4] = {};

  const int ci0 = w * 2, bo0 = ci0 * 1024 + lane * 16;
  const int srow0 = bo0 >> 6, scol0 = bo0 & 63;
#define G_STAGE(buf, kt)                                                              \
  {                                                                                   \
    _Pragma("unroll")                                                                 \
    for (int j = 0; j < 2; ++j) {                                                     \
      const int row = srow0 + j * 16;                                                 \
      async16(Ab + ((size_t)(m0 + row) * 1024 + (kt) * 32) * 2 + scol0,               \
              aTb + (buf) * 8192 + (ci0 + j) * 1024);                                 \
      async16(Bb + ((size_t)(n0 + row) * 1024 + (kt) * 32) * 2 + scol0,               \
              bTb + (buf) * 8192 + (ci0 + j) * 1024);                                 \
    }                                                                                 \
  }

  G_STAGE(0, 0);
  __syncthreads();
  for (int kt = 0; kt < 32; ++kt) {
    const int cur = kt & 1;
    if (kt + 1 < 32) G_STAGE(cur ^ 1, kt + 1);
    bf16x8 af[4], bfr[4];
#pragma unroll
    for (int mi = 0; mi < 4; ++mi)
      af[mi] = *(const bf16x8*)(aTb + cur * 8192 +
               ((wr * 64 + mi * 16 + (lane & 15)) * 32 + (lane >> 4) * 8) * 2);
#pragma unroll
    for (int ni = 0; ni < 4; ++ni)
      bfr[ni] = *(const bf16x8*)(bTb + cur * 8192 +
               ((wc * 64 + ni * 16 + (lane & 15)) * 32 + (lane >> 4) * 8) * 2);
#pragma unroll
    for (int mi = 0; mi < 4; ++mi)
#pragma unroll
      for (int ni = 0; ni < 4; ++ni)
        acc[mi][ni] = __builtin_amdgcn_mfma_f32_16x16x32_bf16(af[mi], bfr[ni], acc[mi][ni], 0, 0, 0);
    __syncthreads();
  }
#undef G_STAGE

  const int mat = n0 >> 10;
  const int nn0 = n0 & 1023;
  if (mat < 2) {
    unsigned short* dst = (mat == 0) ? q_lin : k_lin;
#pragma unroll
    for (int mi = 0; mi < 4; ++mi) {
      const int r0 = m0 + wr * 64 + mi * 16 + (lane >> 4) * 4;
#pragma unroll
      for (int ni = 0; ni < 4; ++ni) {
        const int c = nn0 + wc * 64 + ni * 16 + (lane & 15);
#pragma unroll
        for (int r = 0; r < 4; ++r)
          dst[(size_t)(r0 + r) * 1024 + c] = f2bf(acc[mi][ni][r]);
      }
    }
  } else {
#pragma unroll
    for (int mi = 0; mi < 4; ++mi) {
      const int r0 = m0 + wr * 64 + mi * 16 + (lane >> 4) * 4;
      const int b = r0 >> 11, tt = r0 & 2047;
#pragma unroll
      for (int ni = 0; ni < 4; ++ni) {
        const int c = nn0 + wc * 64 + ni * 16 + (lane & 15);
        const int h = c >> 6, d = c & 63;
        ushort4 o;
        o.x = f2bf(acc[mi][ni][0]); o.y = f2bf(acc[mi][ni][1]);
        o.z = f2bf(acc[mi][ni][2]); o.w = f2bf(acc[mi][ni][3]);
        *(ushort4*)(vT + ((size_t)((b * 16 + h) * 64 + d) << 11) + tt) = o;
      }
    }
  }
}

// ---------- 3) flash attention: 32x32 MFMA, in-register softmax, LDS P round-trip ----------
// grid 1024 WGs (16 t-tiles x 64 bh, XCD-swizzled); 4 waves; 32 q/wave; KVBLK=64.
__global__ __launch_bounds__(256, 3) void k_attn(const unsigned short* __restrict__ q_lin,
                                                 const unsigned short* __restrict__ k_lin,
                                                 const unsigned short* __restrict__ vT,
                                                 const int* __restrict__ mask,
                                                 unsigned short* __restrict__ o_lin) {
  __shared__ __align__(16) unsigned short Kt[2][64 * 64];   // [key][d], swizzled
  __shared__ __align__(16) unsigned short Vt[2][64 * 64];   // [d][key], swizzled
  __shared__ __align__(16) unsigned short Pl[4][32 * 64];   // per-wave P^T [q][key], swizzled
  __shared__ __align__(16) float biasl[2][64];
  const int tid = threadIdx.x, lane = tid & 63, w = tid >> 6;
  const int qi = lane & 31, hi = lane >> 5;
  int flat = blockIdx.y * 16 + blockIdx.x;
  flat = (flat & 7) * 128 + (flat >> 3);          // bijective XCD swizzle (1024%8==0)
  const int bh = flat >> 4, b = bh >> 4, h = bh & 15;
  const int t0 = (flat & 15) * 128;
  const unsigned short* qbp = q_lin + (size_t)b * 2048 * 1024 + h * 64;
  const unsigned short* kbp = k_lin + (size_t)b * 2048 * 1024 + h * 64;
  const unsigned short* vbp = vT + ((size_t)bh * 64 << 11);
  unsigned short* obp = o_lin + (size_t)b * 2048 * 1024 + h * 64;
  const int* mp = mask + b * 2048;
  char* KtB = (char*)Kt; char* VtB = (char*)Vt;
  char* PlB = (char*)(&Pl[w][0]);
  const int rsw = (qi & 7) << 4;                  // read-side XOR swizzle

  // Q fragments in registers: B-frag of S^T = K·Q^T, per d-step s: Q[q][s*16+hi*8 .. +7]
  bf16x8 qf[4];
  {
    const unsigned short* qrow = qbp + (size_t)(t0 + w * 32 + qi) * 1024;
#pragma unroll
    for (int s = 0; s < 4; ++s)
      qf[s] = *(const bf16x8*)(qrow + s * 16 + hi * 8);
  }

  f32x16 oaccA = {}, oaccB = {};                  // O^T: rows d (A: 0..31, B: 32..63), col = own q
  float m_ = -3.0e38f, l_ = 0.f;

  const int sci = w * 2, sbo = sci * 1024 + lane * 16;
  const int srow = sbo >> 7;
  const int scolb = (sbo & 127) ^ ((srow & 7) << 4);   // pre-swizzled source
#define A_STAGE(buf, kv0)                                                             \
  {                                                                                   \
    _Pragma("unroll")                                                                 \
    for (int j = 0; j < 2; ++j) {                                                     \
      const int row = srow + j * 8;                                                   \
      async16(kbp + (size_t)((kv0) + row) * 1024 + (scolb >> 1),                      \
              KtB + (buf) * 8192 + (sci + j) * 1024);                                 \
      async16(vbp + (size_t)row * 2048 + (kv0) + (scolb >> 1),                        \
              VtB + (buf) * 8192 + (sci + j) * 1024);                                 \
    }                                                                                 \
    if (tid < 64) biasl[buf][tid] = (mp[(kv0) + tid] == 0) ? -__builtin_inff() : 0.0f;\
  }

  A_STAGE(0, 0);
  __syncthreads();

  for (int kt = 0; kt < 32; ++kt) {
    const int cur = kt & 1;
    if (kt + 1 < 32) A_STAGE(cur ^ 1, (kt + 1) * 64);

    // ---- S^T = K·Q^T : two 32-key tiles, 4 d-steps each ----
    f32x16 sA = {}, sB = {};
    __builtin_amdgcn_s_setprio(1);
#pragma unroll
    for (int s = 0; s < 4; ++s) {
      bf16x8 kf = *(const bf16x8*)(KtB + cur * 8192 + (qi)*128 + ((s * 32 + hi * 16) ^ rsw));
      sA = __builtin_amdgcn_mfma_f32_32x32x16_bf16(kf, qf[s], sA, 0, 0, 0);
    }
#pragma unroll
    for (int s = 0; s < 4; ++s) {
      bf16x8 kf = *(const bf16x8*)(KtB + cur * 8192 + (32 + qi) * 128 + ((s * 32 + hi * 16) ^ rsw));
      sB = __builtin_amdgcn_mfma_f32_32x32x16_bf16(kf, qf[s], sB, 0, 0, 0);
    }
    __builtin_amdgcn_s_setprio(0);

    // ---- bias (mask) add: lane's keys are 8u + 4*hi + c (+32 for sB) ----
    float e[32];
#pragma unroll
    for (int u = 0; u < 4; ++u) {
      const float4 b4 = ((const float4*)biasl[cur])[2 * u + hi];
      e[4 * u + 0] = sA[4 * u + 0] + b4.x; e[4 * u + 1] = sA[4 * u + 1] + b4.y;
      e[4 * u + 2] = sA[4 * u + 2] + b4.z; e[4 * u + 3] = sA[4 * u + 3] + b4.w;
    }
#pragma unroll
    for (int u = 0; u < 4; ++u) {
      const float4 b4 = ((const float4*)biasl[cur])[8 + 2 * u + hi];
      e[16 + 4 * u + 0] = sB[4 * u + 0] + b4.x; e[16 + 4 * u + 1] = sB[4 * u + 1] + b4.y;
      e[16 + 4 * u + 2] = sB[4 * u + 2] + b4.z; e[16 + 4 * u + 3] = sB[4 * u + 3] + b4.w;
    }

    // ---- row max: tree over 32 in-lane + 1 cross-half shuffle ----
    float t16[16];
#pragma unroll
    for (int i = 0; i < 16; ++i) t16[i] = fmaxf(e[i], e[16 + i]);
#pragma unroll
    for (int i = 0; i < 8; ++i) t16[i] = fmaxf(t16[i], t16[8 + i]);
#pragma unroll
    for (int i = 0; i < 4; ++i) t16[i] = fmaxf(t16[i], t16[4 + i]);
    float mt = fmaxf(fmaxf(t16[0], t16[1]), fmaxf(t16[2], t16[3]));
    mt = fmaxf(mt, __shfl_xor(mt, 32));

    // ---- defer-max (THR=8 in log2 units) ----
    if (__any(mt > m_ + 8.0f)) {
      const float mn = fmaxf(m_, mt);
      const float sf = __builtin_amdgcn_exp2f(m_ - mn);
      m_ = mn; l_ *= sf;
#pragma unroll
      for (int r = 0; r < 16; ++r) { oaccA[r] *= sf; oaccB[r] *= sf; }
    }

    // ---- exp2 + row sum ----
#pragma unroll
    for (int i = 0; i < 32; ++i) e[i] = __builtin_amdgcn_exp2f(e[i] - m_);
    float u16[16];
#pragma unroll
    for (int i = 0; i < 16; ++i) u16[i] = e[i] + e[16 + i];
#pragma unroll
    for (int i = 0; i < 8; ++i) u16[i] += u16[8 + i];
#pragma unroll
    for (int i = 0; i < 4; ++i) u16[i] += u16[4 + i];
    float rs = (u16[0] + u16[1]) + (u16[2] + u16[3]);
    l_ += rs + __shfl_xor(rs, 32);

    // ---- P -> per-wave LDS (swizzled): lane's keys 8u+4hi (+0..3), own row q=qi ----
#pragma unroll
    for (int u = 0; u < 8; ++u) {
      uint2 pk;
      pk.x = pkbf(e[4 * u + 0], e[4 * u + 1]);
      pk.y = pkbf(e[4 * u + 2], e[4 * u + 3]);
      *(uint2*)(PlB + qi * 128 + ((16 * u + 8 * hi) ^ rsw)) = pk;
    }
    // ---- P fragments back: keys 16t+8hi .. +7 for own q ----
    bf16x8 pw[4];
#pragma unroll
    for (int t = 0; t < 4; ++t)
      pw[t] = *(const bf16x8*)(PlB + qi * 128 + ((32 * t + 16 * hi) ^ rsw));

    // ---- O^T += V^T·P^T : 2 d-tiles x 4 k-steps ----
    __builtin_amdgcn_s_setprio(1);
#pragma unroll
    for (int t = 0; t < 4; ++t) {
      bf16x8 vf = *(const bf16x8*)(VtB + cur * 8192 + (qi)*128 + ((t * 32 + hi * 16) ^ rsw));
      oaccA = __builtin_amdgcn_mfma_f32_32x32x16_bf16(vf, pw[t], oaccA, 0, 0, 0);
    }
#pragma unroll
    for (int t = 0; t < 4; ++t) {
      bf16x8 vf = *(const bf16x8*)(VtB + cur * 8192 + (32 + qi) * 128 + ((t * 32 + hi * 16) ^ rsw));
      oaccB = __builtin_amdgcn_mfma_f32_32x32x16_bf16(vf, pw[t], oaccB, 0, 0, 0);
    }
    __builtin_amdgcn_s_setprio(0);
    __syncthreads();
  }
#undef A_STAGE

  // ---- epilogue: lane owns q = t0+w*32+qi; d = m*32 + 8*u + 4*hi + c ----
  const float inv = 1.0f / l_;
  unsigned short* orow = obp + (size_t)(t0 + w * 32 + qi) * 1024;
#pragma unroll
  for (int u = 0; u < 4; ++u) {
    ushort4 oa, ob;
    oa.x = f2bf(oaccA[4 * u + 0] * inv); oa.y = f2bf(oaccA[4 * u + 1] * inv);
    oa.z = f2bf(oaccA[4 * u + 2] * inv); oa.w = f2bf(oaccA[4 * u + 3] * inv);
    ob.x = f2bf(oaccB[4 * u + 0] * inv); ob.y = f2bf(oaccB[4 * u + 1] * inv);
    ob.z = f2bf(oaccB[4 * u + 2] * inv); ob.w = f2bf(oaccB[4 * u + 3] * inv);
    *(ushort4*)(orow + 8 * u + 4 * hi) = oa;
    *(ushort4*)(orow + 32 + 8 * u + 4 * hi) = ob;
  }
}

// ---------- 4) output GEMM + bias -> fp32 (2-phase dbuf, XCD-swizzled) ----------
__global__ __launch_bounds__(256) void k_gemm_out(const unsigned short* __restrict__ A,
                                                  const unsigned short* __restrict__ Bt,
                                                  const float* __restrict__ bias,
                                                  float* __restrict__ out) {
  __shared__ __align__(16) unsigned short aT[2][128 * 32];
  __shared__ __align__(16) unsigned short bT[2][128 * 32];
  const int tid = threadIdx.x, lane = tid & 63, w = tid >> 6;
  const int wr = w >> 1, wc = w & 1;
  int flat = blockIdx.y * 8 + blockIdx.x;          // nwg = 512, %8==0
  flat = (flat & 7) * 64 + (flat >> 3);
  const int m0 = (flat >> 3) * 128, n0 = (flat & 7) * 128;
  const char* Ab = (const char*)A;
  const char* Bb = (const char*)Bt;
  char* aTb = (char*)aT; char* bTb = (char*)bT;
  f32x4 acc[4][4] = {};

  const int ci0 = w * 2, bo0 = ci0 * 1024 + lane * 16;
  const int srow0 = bo0 >> 6, scol0 = bo0 & 63;
#define G_STAGE(buf, kt)                                                              \
  {                                                                                   \
    _Pragma("unroll")                                                                 \
    for (int j = 0; j < 2; ++j) {                                                     \
      const int row = srow0 + j * 16;                                                 \
      async16(Ab + ((size_t)(m0 + row) * 1024 + (kt) * 32) * 2 + scol0,               \
              aTb + (buf) * 8192 + (ci0 + j) * 1024);                                 \
      async16(Bb + ((size_t)(n0 + row) * 1024 + (kt) * 32) * 2 + scol0,               \
              bTb + (buf) * 8192 + (ci0 + j) * 1024);                                 \
    }                                                                                 \
  }

  G_STAGE(0, 0);
  __syncthreads();
  for (int kt = 0; kt < 32; ++kt) {
    const int cur = kt & 1;
    if (kt + 1 < 32) G_STAGE(cur ^ 1, kt + 1);
    bf16x8 af[4], bfr[4];
#pragma unroll
    for (int mi = 0; mi < 4; ++mi)
      af[mi] = *(const bf16x8*)(aTb + cur * 8192 +
               ((wr * 64 + mi * 16 + (lane & 15)) * 32 + (lane >> 4) * 8) * 2);
#pragma unroll
    for (int ni = 0; ni < 4; ++ni)
      bfr[ni] = *(const bf16x8*)(bTb + cur * 8192 +
               ((wc * 64 + ni * 16 + (lane & 15)) * 32 + (lane >> 4) * 8) * 2);
#pragma unroll
    for (int mi = 0; mi < 4; ++mi)
#pragma unroll
      for (int ni = 0; ni < 4; ++ni)
        acc[mi][ni] = __builtin_amdgcn_mfma_f32_16x16x32_bf16(af[mi], bfr[ni], acc[mi][ni], 0, 0, 0);
    __syncthreads();
  }
#undef G_STAGE
#pragma unroll
  for (int mi = 0; mi < 4; ++mi) {
    const int r0 = m0 + wr * 64 + mi * 16 + (lane >> 4) * 4;
#pragma unroll
    for (int ni = 0; ni < 4; ++ni) {
      const int c = n0 + wc * 64 + ni * 16 + (lane & 15);
      const float bb = bias[c];
#pragma unroll
      for (int r = 0; r < 4; ++r)
        out[(size_t)(r0 + r) * 1024 + c] = acc[mi][ni][r] + bb;
    }
  }
}

// ---------- launcher ----------
extern "C" void kernel_launch(void* const* d_in, const int* in_sizes, int n_in,
                              void* d_out, int out_size, void* d_ws, size_t ws_size,
                              hipStream_t stream) {
  const float* hs   = (const float*)d_in[0];
  const int*   mask = (const int*)d_in[1];
  const float* Wq   = (const float*)d_in[2];
  const float* Wk   = (const float*)d_in[3];
  const float* Wv   = (const float*)d_in[4];
  const float* Wo   = (const float*)d_in[5];
  const float* bo   = (const float*)d_in[6];
  float* out = (float*)d_out;

  const size_t MB = 1024 * 1024;
  char* ws = (char*)d_ws;
  unsigned short* hs_bf  = (unsigned short*)(ws);             // 16 MB
  unsigned short* wt_qkv = (unsigned short*)(ws + 16 * MB);   //  6 MB (q pre-scaled)
  unsigned short* wot    = (unsigned short*)(ws + 22 * MB);   //  2 MB
  unsigned short* q_lin  = (unsigned short*)(ws + 24 * MB);   // 16 MB
  unsigned short* k_lin  = (unsigned short*)(ws + 40 * MB);   // 16 MB
  unsigned short* vT     = (unsigned short*)(ws + 56 * MB);   // 16 MB [b][h][d][t]
  unsigned short* o_lin  = (unsigned short*)(ws + 72 * MB);   // 16 MB

  k_prep<<<9216, 256, 0, stream>>>(hs, Wq, Wk, Wv, Wo, hs_bf, wt_qkv, wot);
  k_gemm_qkv<<<dim3(24, 64), 256, 0, stream>>>(hs_bf, wt_qkv, q_lin, k_lin, vT);
  k_attn<<<dim3(16, 64), 256, 0, stream>>>(q_lin, k_lin, vT, mask, o_lin);
  k_gemm_out<<<dim3(8, 64), 256, 0, stream>>>(o_lin, wot, bo, out);
}

// Round 5
// 312.193 us; speedup vs baseline: 1.4227x; 1.0120x over previous
//
#include <hip/hip_runtime.h>
#include <stdint.h>

// ---------- types ----------
typedef __attribute__((ext_vector_type(8))) __bf16 bf16x8;
typedef __attribute__((ext_vector_type(4))) float f32x4;
typedef __attribute__((ext_vector_type(16))) float f32x16;
typedef __attribute__((ext_vector_type(4))) unsigned u32x4;

#define QSCALE 0.18033688011112042f   // 0.125 * log2(e): softmax computed base-2

static __device__ __forceinline__ unsigned short f2bf(float x) {
  return __builtin_bit_cast(unsigned short, (__bf16)x);
}
static __device__ __forceinline__ unsigned pkbf(float a, float b) {
  union { unsigned short h[2]; unsigned u; } r;
  r.h[0] = f2bf(a); r.h[1] = f2bf(b); return r.u;
}
static __device__ __forceinline__ void async16(const void* g, void* l) {
  __builtin_amdgcn_global_load_lds(
      (const __attribute__((address_space(1))) void*)g,
      (__attribute__((address_space(3))) void*)l, 16, 0, 0);
}

// ---------- 1) prep: hidden fp32->bf16 (0..8191) + weight transpose (8192..9215) + mask bias (9216..9219) ----------
__global__ __launch_bounds__(256) void k_prep(const float* __restrict__ hs,
                                              const float* __restrict__ Wq,
                                              const float* __restrict__ Wk,
                                              const float* __restrict__ Wv,
                                              const float* __restrict__ Wo,
                                              const int* __restrict__ mask,
                                              unsigned short* __restrict__ hs_bf,
                                              unsigned short* __restrict__ wt_qkv,
                                              unsigned short* __restrict__ wot,
                                              float* __restrict__ bias_all) {
  __shared__ float tile[64][65];
  const int bid = blockIdx.x;
  if (bid < 8192) {
    const int i = bid * 256 + threadIdx.x;
    float4 v = ((const float4*)hs)[i];
    ushort4 o;
    o.x = f2bf(v.x); o.y = f2bf(v.y); o.z = f2bf(v.z); o.w = f2bf(v.w);
    ((ushort4*)hs_bf)[i] = o;
    return;
  }
  if (bid >= 9216) {
    const int b = bid - 9216;
#pragma unroll
    for (int j = 0; j < 8; ++j) {
      const int t = j * 256 + threadIdx.x;
      bias_all[b * 2048 + t] = (mask[b * 2048 + t] == 0) ? -__builtin_inff() : 0.0f;
    }
    return;
  }
  const int idx = bid - 8192;
  const int mat = idx >> 8;
  const float* W = (mat == 0) ? Wq : (mat == 1) ? Wk : (mat == 2) ? Wv : Wo;
  const float scale = (mat == 0) ? QSCALE : 1.0f;   // attn scale + log2e folded into Wq
  const int n0 = (idx & 15) * 64, k0 = ((idx >> 4) & 15) * 64;
  const int t = threadIdx.x, c = t & 63;
#pragma unroll
  for (int j = 0; j < 16; ++j) {
    int r = j * 4 + (t >> 6);
    tile[r][c] = W[(size_t)(k0 + r) * 1024 + n0 + c] * scale;
  }
  __syncthreads();
  unsigned short* dst = (mat < 3) ? (wt_qkv + (size_t)mat * 1024 * 1024) : wot;
#pragma unroll
  for (int j = 0; j < 16; ++j) {
    int nr = j * 4 + (t >> 6);
    dst[(size_t)(n0 + nr) * 1024 + k0 + c] = f2bf(tile[c][nr]);
  }
}

// ---------- 2) QKV GEMM (2-phase dbuf, XCD-swizzled) ----------
__global__ __launch_bounds__(256) void k_gemm_qkv(const unsigned short* __restrict__ A,
                                                  const unsigned short* __restrict__ Bt,
                                                  unsigned short* __restrict__ q_lin,
                                                  unsigned short* __restrict__ k_lin,
                                                  unsigned short* __restrict__ vT) {
  __shared__ __align__(16) unsigned short aT[2][128 * 32];
  __shared__ __align__(16) unsigned short bT[2][128 * 32];
  const int tid = threadIdx.x, lane = tid & 63, w = tid >> 6;
  const int wr = w >> 1, wc = w & 1;
  // bijective XCD swizzle (nwg = 24*64 = 1536, %8==0)
  int flat = blockIdx.y * 24 + blockIdx.x;
  flat = (flat & 7) * 192 + (flat >> 3);
  const int m0 = (flat / 24) * 128, n0 = (flat % 24) * 128;
  const char* Ab = (const char*)A;
  const char* Bb = (const char*)Bt;
  char* aTb = (char*)aT; char* bTb = (char*)bT;
  f32x4 acc[4][4] = {};

  const int ci0 = w * 2, bo0 = ci0 * 1024 + lane * 16;
  const int srow0 = bo0 >> 6, scol0 = bo0 & 63;
#define G_STAGE(buf, kt)                                                              \
  {                                                                                   \
    _Pragma("unroll")                                                                 \
    for (int j = 0; j < 2; ++j) {                                                     \
      const int row = srow0 + j * 16;                                                 \
      async16(Ab + ((size_t)(m0 + row) * 1024 + (kt) * 32) * 2 + scol0,               \
              aTb + (buf) * 8192 + (ci0 + j) * 1024);                                 \
      async16(Bb + ((size_t)(n0 + row) * 1024 + (kt) * 32) * 2 + scol0,               \
              bTb + (buf) * 8192 + (ci0 + j) * 1024);                                 \
    }                                                                                 \
  }

  G_STAGE(0, 0);
  __syncthreads();
  for (int kt = 0; kt < 32; ++kt) {
    const int cur = kt & 1;
    if (kt + 1 < 32) G_STAGE(cur ^ 1, kt + 1);
    bf16x8 af[4], bfr[4];
#pragma unroll
    for (int mi = 0; mi < 4; ++mi)
      af[mi] = *(const bf16x8*)(aTb + cur * 8192 +
               ((wr * 64 + mi * 16 + (lane & 15)) * 32 + (lane >> 4) * 8) * 2);
#pragma unroll
    for (int ni = 0; ni < 4; ++ni)
      bfr[ni] = *(const bf16x8*)(bTb + cur * 8192 +
               ((wc * 64 + ni * 16 + (lane & 15)) * 32 + (lane >> 4) * 8) * 2);
#pragma unroll
    for (int mi = 0; mi < 4; ++mi)
#pragma unroll
      for (int ni = 0; ni < 4; ++ni)
        acc[mi][ni] = __builtin_amdgcn_mfma_f32_16x16x32_bf16(af[mi], bfr[ni], acc[mi][ni], 0, 0, 0);
    __syncthreads();
  }
#undef G_STAGE

  const int mat = n0 >> 10;
  const int nn0 = n0 & 1023;
  if (mat < 2) {
    unsigned short* dst = (mat == 0) ? q_lin : k_lin;
#pragma unroll
    for (int mi = 0; mi < 4; ++mi) {
      const int r0 = m0 + wr * 64 + mi * 16 + (lane >> 4) * 4;
#pragma unroll
      for (int ni = 0; ni < 4; ++ni) {
        const int c = nn0 + wc * 64 + ni * 16 + (lane & 15);
#pragma unroll
        for (int r = 0; r < 4; ++r)
          dst[(size_t)(r0 + r) * 1024 + c] = f2bf(acc[mi][ni][r]);
      }
    }
  } else {
#pragma unroll
    for (int mi = 0; mi < 4; ++mi) {
      const int r0 = m0 + wr * 64 + mi * 16 + (lane >> 4) * 4;
      const int b = r0 >> 11, tt = r0 & 2047;
#pragma unroll
      for (int ni = 0; ni < 4; ++ni) {
        const int c = nn0 + wc * 64 + ni * 16 + (lane & 15);
        const int h = c >> 6, d = c & 63;
        ushort4 o;
        o.x = f2bf(acc[mi][ni][0]); o.y = f2bf(acc[mi][ni][1]);
        o.z = f2bf(acc[mi][ni][2]); o.w = f2bf(acc[mi][ni][3]);
        *(ushort4*)(vT + ((size_t)((b * 16 + h) * 64 + d) << 11) + tt) = o;
      }
    }
  }
}

// ---------- 3) flash attention: 32x32 MFMA, in-register softmax, shfl P redistribution ----------
// grid 1024 WGs (16 t-tiles x 64 bh, XCD-swizzled); 4 waves; 32 q/wave; KVBLK=64.
__global__ __launch_bounds__(256, 4) void k_attn(const unsigned short* __restrict__ q_lin,
                                                 const unsigned short* __restrict__ k_lin,
                                                 const unsigned short* __restrict__ vT,
                                                 const float* __restrict__ bias_all,
                                                 unsigned short* __restrict__ o_lin) {
  __shared__ __align__(16) unsigned short Kt[2][64 * 64];   // [key][d], swizzled
  __shared__ __align__(16) unsigned short Vt[2][64 * 64];   // [d][key], swizzled
  __shared__ __align__(16) float biasl[2][64];
  const int tid = threadIdx.x, lane = tid & 63, w = tid >> 6;
  const int qi = lane & 31, hi = lane >> 5;
  int flat = blockIdx.y * 16 + blockIdx.x;
  flat = (flat & 7) * 128 + (flat >> 3);          // bijective XCD swizzle (1024%8==0)
  const int bh = flat >> 4, b = bh >> 4, h = bh & 15;
  const int t0 = (flat & 15) * 128;
  const unsigned short* qbp = q_lin + (size_t)b * 2048 * 1024 + h * 64;
  const unsigned short* kbp = k_lin + (size_t)b * 2048 * 1024 + h * 64;
  const unsigned short* vbp = vT + ((size_t)bh * 64 << 11);
  unsigned short* obp = o_lin + (size_t)b * 2048 * 1024 + h * 64;
  const char* bbp = (const char*)(bias_all + b * 2048);
  char* KtB = (char*)Kt; char* VtB = (char*)Vt;
  char* blB = (char*)biasl;
  const int rsw = (qi & 7) << 4;                  // read-side XOR swizzle

  // Q fragments in registers: B-frag of S^T = K·Q^T, per d-step s: Q[q][s*16+hi*8 .. +7]
  bf16x8 qf[4];
  {
    const unsigned short* qrow = qbp + (size_t)(t0 + w * 32 + qi) * 1024;
#pragma unroll
    for (int s = 0; s < 4; ++s)
      qf[s] = *(const bf16x8*)(qrow + s * 16 + hi * 8);
  }

  f32x16 oaccA = {}, oaccB = {};                  // O^T: rows d (A: 0..31, B: 32..63), col = own q
  float m_ = -3.0e38f, l_ = 0.f;

  const int sci = w * 2, sbo = sci * 1024 + lane * 16;
  const int srow = sbo >> 7;
  const int scolb = (sbo & 127) ^ ((srow & 7) << 4);   // pre-swizzled source
#define A_STAGE(buf, kv0)                                                             \
  {                                                                                   \
    _Pragma("unroll")                                                                 \
    for (int j = 0; j < 2; ++j) {                                                     \
      const int row = srow + j * 8;                                                   \
      async16(kbp + (size_t)((kv0) + row) * 1024 + (scolb >> 1),                      \
              KtB + (buf) * 8192 + (sci + j) * 1024);                                 \
      async16(vbp + (size_t)row * 2048 + (kv0) + (scolb >> 1),                        \
              VtB + (buf) * 8192 + (sci + j) * 1024);                                 \
    }                                                                                 \
    if (lane < 16) async16(bbp + (size_t)(kv0) * 4 + lane * 16,                       \
                           blB + (buf) * 256 + lane * 16);                            \
  }

  A_STAGE(0, 0);
  __syncthreads();

  for (int kt = 0; kt < 32; ++kt) {
    const int cur = kt & 1;
    if (kt + 1 < 32) A_STAGE(cur ^ 1, (kt + 1) * 64);

    // ---- S^T = K·Q^T : two 32-key tiles, 4 d-steps each ----
    f32x16 sA = {}, sB = {};
    __builtin_amdgcn_s_setprio(1);
#pragma unroll
    for (int s = 0; s < 4; ++s) {
      bf16x8 kf = *(const bf16x8*)(KtB + cur * 8192 + (qi)*128 + ((s * 32 + hi * 16) ^ rsw));
      sA = __builtin_amdgcn_mfma_f32_32x32x16_bf16(kf, qf[s], sA, 0, 0, 0);
    }
#pragma unroll
    for (int s = 0; s < 4; ++s) {
      bf16x8 kf = *(const bf16x8*)(KtB + cur * 8192 + (32 + qi) * 128 + ((s * 32 + hi * 16) ^ rsw));
      sB = __builtin_amdgcn_mfma_f32_32x32x16_bf16(kf, qf[s], sB, 0, 0, 0);
    }
    __builtin_amdgcn_s_setprio(0);

    // ---- bias (mask) add: lane's keys are 8u + 4*hi + c (+32 for sB) ----
    float e[32];
#pragma unroll
    for (int u = 0; u < 4; ++u) {
      const float4 b4 = ((const float4*)biasl[cur])[2 * u + hi];
      e[4 * u + 0] = sA[4 * u + 0] + b4.x; e[4 * u + 1] = sA[4 * u + 1] + b4.y;
      e[4 * u + 2] = sA[4 * u + 2] + b4.z; e[4 * u + 3] = sA[4 * u + 3] + b4.w;
    }
#pragma unroll
    for (int u = 0; u < 4; ++u) {
      const float4 b4 = ((const float4*)biasl[cur])[8 + 2 * u + hi];
      e[16 + 4 * u + 0] = sB[4 * u + 0] + b4.x; e[16 + 4 * u + 1] = sB[4 * u + 1] + b4.y;
      e[16 + 4 * u + 2] = sB[4 * u + 2] + b4.z; e[16 + 4 * u + 3] = sB[4 * u + 3] + b4.w;
    }

    // ---- row max: tree over 32 in-lane + 1 cross-half shuffle ----
    float t16[16];
#pragma unroll
    for (int i = 0; i < 16; ++i) t16[i] = fmaxf(e[i], e[16 + i]);
#pragma unroll
    for (int i = 0; i < 8; ++i) t16[i] = fmaxf(t16[i], t16[8 + i]);
#pragma unroll
    for (int i = 0; i < 4; ++i) t16[i] = fmaxf(t16[i], t16[4 + i]);
    float mt = fmaxf(fmaxf(t16[0], t16[1]), fmaxf(t16[2], t16[3]));
    mt = fmaxf(mt, __shfl_xor(mt, 32));

    // ---- defer-max (THR=8 in log2 units) ----
    if (__any(mt > m_ + 8.0f)) {
      const float mn = fmaxf(m_, mt);
      const float sf = __builtin_amdgcn_exp2f(m_ - mn);
      m_ = mn; l_ *= sf;
#pragma unroll
      for (int r = 0; r < 16; ++r) { oaccA[r] *= sf; oaccB[r] *= sf; }
    }

    // ---- exp2 + row sum ----
#pragma unroll
    for (int i = 0; i < 32; ++i) e[i] = __builtin_amdgcn_exp2f(e[i] - m_);
    float u16[16];
#pragma unroll
    for (int i = 0; i < 16; ++i) u16[i] = e[i] + e[16 + i];
#pragma unroll
    for (int i = 0; i < 8; ++i) u16[i] += u16[8 + i];
#pragma unroll
    for (int i = 0; i < 4; ++i) u16[i] += u16[4 + i];
    float rs = (u16[0] + u16[1]) + (u16[2] + u16[3]);
    l_ += rs + __shfl_xor(rs, 32);

    // ---- pack P: quad j of lane (qi,hi) = keys 8j+4hi+0..3 ----
    unsigned d[16];
#pragma unroll
    for (int j = 0; j < 8; ++j) {
      d[2 * j] = pkbf(e[4 * j + 0], e[4 * j + 1]);
      d[2 * j + 1] = pkbf(e[4 * j + 2], e[4 * j + 3]);
    }
    // ---- exchange with lane^32: partner needs quad (2t + partner_hi^1) = our d[4t+2(hi^1)+s] ----
    unsigned rcv[8];
#pragma unroll
    for (int t = 0; t < 4; ++t)
#pragma unroll
      for (int s = 0; s < 2; ++s) {
        const unsigned snd = hi ? d[4 * t + s] : d[4 * t + 2 + s];
        rcv[2 * t + s] = __shfl_xor(snd, 32);
      }
    // ---- assemble PV B-fragments: pw[t] = keys 16t+8hi+0..7 for column q=qi ----
    bf16x8 pw[4];
#pragma unroll
    for (int t = 0; t < 4; ++t) {
      u32x4 u4;
      u4.x = hi ? rcv[2 * t + 0] : d[4 * t + 0];
      u4.y = hi ? rcv[2 * t + 1] : d[4 * t + 1];
      u4.z = hi ? d[4 * t + 2] : rcv[2 * t + 0];
      u4.w = hi ? d[4 * t + 3] : rcv[2 * t + 1];
      pw[t] = __builtin_bit_cast(bf16x8, u4);
    }

    // ---- O^T += V^T·P^T : 2 d-tiles x 4 k-steps ----
    __builtin_amdgcn_s_setprio(1);
#pragma unroll
    for (int t = 0; t < 4; ++t) {
      bf16x8 vf = *(const bf16x8*)(VtB + cur * 8192 + (qi)*128 + ((t * 32 + hi * 16) ^ rsw));
      oaccA = __builtin_amdgcn_mfma_f32_32x32x16_bf16(vf, pw[t], oaccA, 0, 0, 0);
    }
#pragma unroll
    for (int t = 0; t < 4; ++t) {
      bf16x8 vf = *(const bf16x8*)(VtB + cur * 8192 + (32 + qi) * 128 + ((t * 32 + hi * 16) ^ rsw));
      oaccB = __builtin_amdgcn_mfma_f32_32x32x16_bf16(vf, pw[t], oaccB, 0, 0, 0);
    }
    __builtin_amdgcn_s_setprio(0);
    __syncthreads();
  }
#undef A_STAGE

  // ---- epilogue: lane owns q = t0+w*32+qi; d = m*32 + 8*u + 4*hi + c ----
  const float inv = 1.0f / l_;
  unsigned short* orow = obp + (size_t)(t0 + w * 32 + qi) * 1024;
#pragma unroll
  for (int u = 0; u < 4; ++u) {
    ushort4 oa, ob;
    oa.x = f2bf(oaccA[4 * u + 0] * inv); oa.y = f2bf(oaccA[4 * u + 1] * inv);
    oa.z = f2bf(oaccA[4 * u + 2] * inv); oa.w = f2bf(oaccA[4 * u + 3] * inv);
    ob.x = f2bf(oaccB[4 * u + 0] * inv); ob.y = f2bf(oaccB[4 * u + 1] * inv);
    ob.z = f2bf(oaccB[4 * u + 2] * inv); ob.w = f2bf(oaccB[4 * u + 3] * inv);
    *(ushort4*)(orow + 8 * u + 4 * hi) = oa;
    *(ushort4*)(orow + 32 + 8 * u + 4 * hi) = ob;
  }
}

// ---------- 4) output GEMM + bias -> fp32 (2-phase dbuf, XCD-swizzled) ----------
__global__ __launch_bounds__(256) void k_gemm_out(const unsigned short* __restrict__ A,
                                                  const unsigned short* __restrict__ Bt,
                                                  const float* __restrict__ bias,
                                                  float* __restrict__ out) {
  __shared__ __align__(16) unsigned short aT[2][128 * 32];
  __shared__ __align__(16) unsigned short bT[2][128 * 32];
  const int tid = threadIdx.x, lane = tid & 63, w = tid >> 6;
  const int wr = w >> 1, wc = w & 1;
  int flat = blockIdx.y * 8 + blockIdx.x;          // nwg = 512, %8==0
  flat = (flat & 7) * 64 + (flat >> 3);
  const int m0 = (flat >> 3) * 128, n0 = (flat & 7) * 128;
  const char* Ab = (const char*)A;
  const char* Bb = (const char*)Bt;
  char* aTb = (char*)aT; char* bTb = (char*)bT;
  f32x4 acc[4][4] = {};

  const int ci0 = w * 2, bo0 = ci0 * 1024 + lane * 16;
  const int srow0 = bo0 >> 6, scol0 = bo0 & 63;
#define G_STAGE(buf, kt)                                                              \
  {                                                                                   \
    _Pragma("unroll")                                                                 \
    for (int j = 0; j < 2; ++j) {                                                     \
      const int row = srow0 + j * 16;                                                 \
      async16(Ab + ((size_t)(m0 + row) * 1024 + (kt) * 32) * 2 + scol0,               \
              aTb + (buf) * 8192 + (ci0 + j) * 1024);                                 \
      async16(Bb + ((size_t)(n0 + row) * 1024 + (kt) * 32) * 2 + scol0,               \
              bTb + (buf) * 8192 + (ci0 + j) * 1024);                                 \
    }                                                                                 \
  }

  G_STAGE(0, 0);
  __syncthreads();
  for (int kt = 0; kt < 32; ++kt) {
    const int cur = kt & 1;
    if (kt + 1 < 32) G_STAGE(cur ^ 1, kt + 1);
    bf16x8 af[4], bfr[4];
#pragma unroll
    for (int mi = 0; mi < 4; ++mi)
      af[mi] = *(const bf16x8*)(aTb + cur * 8192 +
               ((wr * 64 + mi * 16 + (lane & 15)) * 32 + (lane >> 4) * 8) * 2);
#pragma unroll
    for (int ni = 0; ni < 4; ++ni)
      bfr[ni] = *(const bf16x8*)(bTb + cur * 8192 +
               ((wc * 64 + ni * 16 + (lane & 15)) * 32 + (lane >> 4) * 8) * 2);
#pragma unroll
    for (int mi = 0; mi < 4; ++mi)
#pragma unroll
      for (int ni = 0; ni < 4; ++ni)
        acc[mi][ni] = __builtin_amdgcn_mfma_f32_16x16x32_bf16(af[mi], bfr[ni], acc[mi][ni], 0, 0, 0);
    __syncthreads();
  }
#undef G_STAGE
#pragma unroll
  for (int mi = 0; mi < 4; ++mi) {
    const int r0 = m0 + wr * 64 + mi * 16 + (lane >> 4) * 4;
#pragma unroll
    for (int ni = 0; ni < 4; ++ni) {
      const int c = n0 + wc * 64 + ni * 16 + (lane & 15);
      const float bb = bias[c];
#pragma unroll
      for (int r = 0; r < 4; ++r)
        out[(size_t)(r0 + r) * 1024 + c] = acc[mi][ni][r] + bb;
    }
  }
}

// ---------- launcher ----------
extern "C" void kernel_launch(void* const* d_in, const int* in_sizes, int n_in,
                              void* d_out, int out_size, void* d_ws, size_t ws_size,
                              hipStream_t stream) {
  const float* hs   = (const float*)d_in[0];
  const int*   mask = (const int*)d_in[1];
  const float* Wq   = (const float*)d_in[2];
  const float* Wk   = (const float*)d_in[3];
  const float* Wv   = (const float*)d_in[4];
  const float* Wo   = (const float*)d_in[5];
  const float* bo   = (const float*)d_in[6];
  float* out = (float*)d_out;

  const size_t MB = 1024 * 1024;
  char* ws = (char*)d_ws;
  unsigned short* hs_bf  = (unsigned short*)(ws);             // 16 MB
  unsigned short* wt_qkv = (unsigned short*)(ws + 16 * MB);   //  6 MB (q pre-scaled)
  unsigned short* wot    = (unsigned short*)(ws + 22 * MB);   //  2 MB
  unsigned short* q_lin  = (unsigned short*)(ws + 24 * MB);   // 16 MB
  unsigned short* k_lin  = (unsigned short*)(ws + 40 * MB);   // 16 MB
  unsigned short* vT     = (unsigned short*)(ws + 56 * MB);   // 16 MB [b][h][d][t]
  unsigned short* o_lin  = (unsigned short*)(ws + 72 * MB);   // 16 MB
  float*          bias_a = (float*)(ws + 88 * MB);            // 32 KB [4][2048]

  k_prep<<<9220, 256, 0, stream>>>(hs, Wq, Wk, Wv, Wo, mask, hs_bf, wt_qkv, wot, bias_a);
  k_gemm_qkv<<<dim3(24, 64), 256, 0, stream>>>(hs_bf, wt_qkv, q_lin, k_lin, vT);
  k_attn<<<dim3(16, 64), 256, 0, stream>>>(q_lin, k_lin, vT, bias_a, o_lin);
  k_gemm_out<<<dim3(8, 64), 256, 0, stream>>>(o_lin, wot, bo, out);
}

// Round 6
// 301.426 us; speedup vs baseline: 1.4735x; 1.0357x over previous
//
#include <hip/hip_runtime.h>
#include <stdint.h>

// ---------- types ----------
typedef __attribute__((ext_vector_type(8))) __bf16 bf16x8;
typedef __attribute__((ext_vector_type(4))) float f32x4;
typedef __attribute__((ext_vector_type(16))) float f32x16;
typedef __attribute__((ext_vector_type(4))) unsigned u32x4;

#define QSCALE 0.18033688011112042f   // 0.125 * log2(e): softmax computed base-2

static __device__ __forceinline__ unsigned short f2bf(float x) {
  return __builtin_bit_cast(unsigned short, (__bf16)x);
}
static __device__ __forceinline__ unsigned pkbf(float a, float b) {
  union { unsigned short h[2]; unsigned u; } r;
  r.h[0] = f2bf(a); r.h[1] = f2bf(b); return r.u;
}
static __device__ __forceinline__ void async16(const void* g, void* l) {
  __builtin_amdgcn_global_load_lds(
      (const __attribute__((address_space(1))) void*)g,
      (__attribute__((address_space(3))) void*)l, 16, 0, 0);
}
// involution: swap bits 2 and 3 (key permutation within 32-blocks)
static __device__ __forceinline__ int bsw23(int t) {
  return (t & ~12) | ((t & 4) << 1) | ((t & 8) >> 1);
}

// ---------- 1) prep: hidden fp32->bf16 (0..8191) + weight transpose (8192..9215) + mask bias (9216..9219) ----------
__global__ __launch_bounds__(256) void k_prep(const float* __restrict__ hs,
                                              const float* __restrict__ Wq,
                                              const float* __restrict__ Wk,
                                              const float* __restrict__ Wv,
                                              const float* __restrict__ Wo,
                                              const int* __restrict__ mask,
                                              unsigned short* __restrict__ hs_bf,
                                              unsigned short* __restrict__ wt_qkv,
                                              unsigned short* __restrict__ wot,
                                              float* __restrict__ bias_all) {
  __shared__ float tile[64][65];
  const int bid = blockIdx.x;
  if (bid < 8192) {
    const int i = bid * 256 + threadIdx.x;
    float4 v = ((const float4*)hs)[i];
    ushort4 o;
    o.x = f2bf(v.x); o.y = f2bf(v.y); o.z = f2bf(v.z); o.w = f2bf(v.w);
    ((ushort4*)hs_bf)[i] = o;
    return;
  }
  if (bid >= 9216) {
    const int b = bid - 9216;
#pragma unroll
    for (int j = 0; j < 8; ++j) {
      const int t = j * 256 + threadIdx.x;
      bias_all[b * 2048 + t] = (mask[b * 2048 + t] == 0) ? -__builtin_inff() : 0.0f;
    }
    return;
  }
  const int idx = bid - 8192;
  const int mat = idx >> 8;
  const float* W = (mat == 0) ? Wq : (mat == 1) ? Wk : (mat == 2) ? Wv : Wo;
  const float scale = (mat == 0) ? QSCALE : 1.0f;   // attn scale + log2e folded into Wq
  const int n0 = (idx & 15) * 64, k0 = ((idx >> 4) & 15) * 64;
  const int t = threadIdx.x, c = t & 63;
#pragma unroll
  for (int j = 0; j < 16; ++j) {
    int r = j * 4 + (t >> 6);
    tile[r][c] = W[(size_t)(k0 + r) * 1024 + n0 + c] * scale;
  }
  __syncthreads();
  unsigned short* dst = (mat < 3) ? (wt_qkv + (size_t)mat * 1024 * 1024) : wot;
#pragma unroll
  for (int j = 0; j < 16; ++j) {
    int nr = j * 4 + (t >> 6);
    dst[(size_t)(n0 + nr) * 1024 + k0 + c] = f2bf(tile[c][nr]);
  }
}

// ---------- 2) QKV GEMM (2-phase dbuf, XCD-swizzled) ----------
// outputs: qG[bh][g=d/8][t][d%8], kG same but t bitswap23-permuted, vG[bh][t/8][d][t%8]
__global__ __launch_bounds__(256) void k_gemm_qkv(const unsigned short* __restrict__ A,
                                                  const unsigned short* __restrict__ Bt,
                                                  unsigned short* __restrict__ qG,
                                                  unsigned short* __restrict__ kG,
                                                  unsigned short* __restrict__ vG) {
  __shared__ __align__(16) unsigned short aT[2][128 * 32];
  __shared__ __align__(16) unsigned short bT[2][128 * 32];
  const int tid = threadIdx.x, lane = tid & 63, w = tid >> 6;
  const int wr = w >> 1, wc = w & 1;
  // bijective XCD swizzle (nwg = 24*64 = 1536, %8==0)
  int flat = blockIdx.y * 24 + blockIdx.x;
  flat = (flat & 7) * 192 + (flat >> 3);
  const int m0 = (flat / 24) * 128, n0 = (flat % 24) * 128;
  const char* Ab = (const char*)A;
  const char* Bb = (const char*)Bt;
  char* aTb = (char*)aT; char* bTb = (char*)bT;
  f32x4 acc[4][4] = {};

  const int ci0 = w * 2, bo0 = ci0 * 1024 + lane * 16;
  const int srow0 = bo0 >> 6, scol0 = bo0 & 63;
#define G_STAGE(buf, kt)                                                              \
  {                                                                                   \
    _Pragma("unroll")                                                                 \
    for (int j = 0; j < 2; ++j) {                                                     \
      const int row = srow0 + j * 16;                                                 \
      async16(Ab + ((size_t)(m0 + row) * 1024 + (kt) * 32) * 2 + scol0,               \
              aTb + (buf) * 8192 + (ci0 + j) * 1024);                                 \
      async16(Bb + ((size_t)(n0 + row) * 1024 + (kt) * 32) * 2 + scol0,               \
              bTb + (buf) * 8192 + (ci0 + j) * 1024);                                 \
    }                                                                                 \
  }

  G_STAGE(0, 0);
  __syncthreads();
  for (int kt = 0; kt < 32; ++kt) {
    const int cur = kt & 1;
    if (kt + 1 < 32) G_STAGE(cur ^ 1, kt + 1);
    bf16x8 af[4], bfr[4];
#pragma unroll
    for (int mi = 0; mi < 4; ++mi)
      af[mi] = *(const bf16x8*)(aTb + cur * 8192 +
               ((wr * 64 + mi * 16 + (lane & 15)) * 32 + (lane >> 4) * 8) * 2);
#pragma unroll
    for (int ni = 0; ni < 4; ++ni)
      bfr[ni] = *(const bf16x8*)(bTb + cur * 8192 +
               ((wc * 64 + ni * 16 + (lane & 15)) * 32 + (lane >> 4) * 8) * 2);
#pragma unroll
    for (int mi = 0; mi < 4; ++mi)
#pragma unroll
      for (int ni = 0; ni < 4; ++ni)
        acc[mi][ni] = __builtin_amdgcn_mfma_f32_16x16x32_bf16(af[mi], bfr[ni], acc[mi][ni], 0, 0, 0);
    __syncthreads();
  }
#undef G_STAGE

  const int mat = n0 >> 10;
  const int nn0 = n0 & 1023;
  if (mat < 2) {
    unsigned short* dst = (mat == 0) ? qG : kG;
#pragma unroll
    for (int mi = 0; mi < 4; ++mi) {
      const int r0 = m0 + wr * 64 + mi * 16 + (lane >> 4) * 4;
      const int b = r0 >> 11, tt = r0 & 2047;
      const int pt = (mat == 0) ? tt : bsw23(tt);
#pragma unroll
      for (int ni = 0; ni < 4; ++ni) {
        const int c = nn0 + wc * 64 + ni * 16 + (lane & 15);
        const int h = c >> 6, d = c & 63, g = d >> 3, dm = d & 7;
        const size_t base = (((size_t)(b * 16 + h) * 8 + g) * 2048 + pt) * 8 + dm;
#pragma unroll
        for (int r = 0; r < 4; ++r)
          dst[base + (size_t)r * 8] = f2bf(acc[mi][ni][r]);
      }
    }
  } else {
#pragma unroll
    for (int mi = 0; mi < 4; ++mi) {
      const int r0 = m0 + wr * 64 + mi * 16 + (lane >> 4) * 4;
      const int b = r0 >> 11, tt = r0 & 2047;
      const int tg = tt >> 3, tm = tt & 7;
#pragma unroll
      for (int ni = 0; ni < 4; ++ni) {
        const int c = nn0 + wc * 64 + ni * 16 + (lane & 15);
        const int h = c >> 6, d = c & 63;
        ushort4 o;
        o.x = f2bf(acc[mi][ni][0]); o.y = f2bf(acc[mi][ni][1]);
        o.z = f2bf(acc[mi][ni][2]); o.w = f2bf(acc[mi][ni][3]);
        *(ushort4*)(vG + ((((size_t)(b * 16 + h) * 256 + tg) * 64 + d) * 8 + tm)) = o;
      }
    }
  }
}

// ---------- 3) flash attention: 32x32 MFMA, granule-major LDS (conflict-free), no P exchange ----------
// grid 1024 WGs (16 t-tiles x 64 bh, XCD-swizzled); 4 waves; 32 q/wave; KVBLK=64.
__global__ __launch_bounds__(256, 4) void k_attn(const unsigned short* __restrict__ qG,
                                                 const unsigned short* __restrict__ kG,
                                                 const unsigned short* __restrict__ vG,
                                                 const float* __restrict__ bias_all,
                                                 unsigned short* __restrict__ o_lin) {
  __shared__ __align__(16) unsigned short Kt[2][4096];   // [g=d/8][key(perm'd)][8]
  __shared__ __align__(16) unsigned short Vt[2][4096];   // [kg=key/8][d][8]
  __shared__ __align__(16) float biasl[2][64];
  const int tid = threadIdx.x, lane = tid & 63, w = tid >> 6;
  const int qi = lane & 31, hi = lane >> 5;
  int flat = blockIdx.y * 16 + blockIdx.x;
  flat = (flat & 7) * 128 + (flat >> 3);          // bijective XCD swizzle (1024%8==0)
  const int bh = flat >> 4, b = bh >> 4, h = bh & 15;
  const int t0 = (flat & 15) * 128;
  const char* qGb = (const char*)(qG + (size_t)bh * 131072);
  const char* kGb = (const char*)(kG + (size_t)bh * 131072);
  const char* vGb = (const char*)(vG + (size_t)bh * 131072);
  unsigned short* obp = o_lin + (size_t)b * 2048 * 1024 + h * 64;
  const char* bbp = (const char*)(bias_all + b * 2048);
  char* KtB = (char*)Kt; char* VtB = (char*)Vt;
  char* blB = (char*)biasl;

  // Q fragments: B-frag of S^T = K·Q^T; step s needs Q[q][d = s*16 + hi*8 .. +7]
  const int qrow = t0 + w * 32 + qi;
  bf16x8 qf[4];
#pragma unroll
  for (int s = 0; s < 4; ++s)
    qf[s] = *(const bf16x8*)(qGb + ((size_t)((2 * s + hi) * 2048 + qrow)) * 16);

  f32x16 oaccA = {}, oaccB = {};                  // O^T: rows d (A: 0..31, B: 32..63), col = own q
  float m_ = -3.0e38f, l_ = 0.f;

  const int g0 = w * 2;                            // this wave's 2 staging granules
#define A_STAGE(buf, kv0)                                                             \
  {                                                                                   \
    _Pragma("unroll")                                                                 \
    for (int j = 0; j < 2; ++j) {                                                     \
      const int g = g0 + j;                                                           \
      async16(kGb + ((size_t)(g * 2048 + (kv0) + lane)) * 16,                         \
              KtB + (buf) * 8192 + g * 1024);                                         \
      async16(vGb + ((size_t)((kv0) * 8 + g * 64 + lane)) * 16,                       \
              VtB + (buf) * 8192 + g * 1024);                                         \
    }                                                                                 \
    if (lane < 16) async16(bbp + (size_t)(kv0) * 4 + lane * 16,                       \
                           blB + (buf) * 256 + lane * 16);                            \
  }

  A_STAGE(0, 0);
  __syncthreads();

#pragma unroll 2
  for (int kt = 0; kt < 32; ++kt) {
    const int cur = kt & 1;
    if (kt + 1 < 32) A_STAGE(cur ^ 1, (kt + 1) * 64);

    // ---- S^T = K·Q^T : two 32-key tiles, 4 d-steps each; contiguous LDS reads ----
    const char* Kb = KtB + cur * 8192 + qi * 16 + hi * 1024;
    f32x16 sA = {}, sB = {};
    __builtin_amdgcn_s_setprio(1);
#pragma unroll
    for (int s = 0; s < 4; ++s) {
      bf16x8 kf = *(const bf16x8*)(Kb + s * 2048);
      sA = __builtin_amdgcn_mfma_f32_32x32x16_bf16(kf, qf[s], sA, 0, 0, 0);
    }
#pragma unroll
    for (int s = 0; s < 4; ++s) {
      bf16x8 kf = *(const bf16x8*)(Kb + s * 2048 + 512);
      sB = __builtin_amdgcn_mfma_f32_32x32x16_bf16(kf, qf[s], sB, 0, 0, 0);
    }
    __builtin_amdgcn_s_setprio(0);

    // ---- bias add: e[4u+c] <-> physical key {0,4,16,20}[u] + 8*hi + c (sB: +32) ----
    float e[32];
#pragma unroll
    for (int u = 0; u < 4; ++u) {
      const int f4 = ((u & 2) << 1) + (u & 1) + (hi << 1);    // {0,1,4,5} + 2hi
      const float4 b4 = ((const float4*)(blB + cur * 256))[f4];
      e[4 * u + 0] = sA[4 * u + 0] + b4.x; e[4 * u + 1] = sA[4 * u + 1] + b4.y;
      e[4 * u + 2] = sA[4 * u + 2] + b4.z; e[4 * u + 3] = sA[4 * u + 3] + b4.w;
      const float4 c4 = ((const float4*)(blB + cur * 256))[f4 + 8];
      e[16 + 4 * u + 0] = sB[4 * u + 0] + c4.x; e[16 + 4 * u + 1] = sB[4 * u + 1] + c4.y;
      e[16 + 4 * u + 2] = sB[4 * u + 2] + c4.z; e[16 + 4 * u + 3] = sB[4 * u + 3] + c4.w;
    }

    // ---- row max: tree over 32 in-lane + 1 cross-half shuffle ----
    float t16[16];
#pragma unroll
    for (int i = 0; i < 16; ++i) t16[i] = fmaxf(e[i], e[16 + i]);
#pragma unroll
    for (int i = 0; i < 8; ++i) t16[i] = fmaxf(t16[i], t16[8 + i]);
#pragma unroll
    for (int i = 0; i < 4; ++i) t16[i] = fmaxf(t16[i], t16[4 + i]);
    float mt = fmaxf(fmaxf(t16[0], t16[1]), fmaxf(t16[2], t16[3]));
    mt = fmaxf(mt, __shfl_xor(mt, 32));

    // ---- defer-max (THR=8 in log2 units) ----
    if (__any(mt > m_ + 8.0f)) {
      const float mn = fmaxf(m_, mt);
      const float sf = __builtin_amdgcn_exp2f(m_ - mn);
      m_ = mn; l_ *= sf;
#pragma unroll
      for (int r = 0; r < 16; ++r) { oaccA[r] *= sf; oaccB[r] *= sf; }
    }

    // ---- exp2 + row sum ----
#pragma unroll
    for (int i = 0; i < 32; ++i) e[i] = __builtin_amdgcn_exp2f(e[i] - m_);
    float u16[16];
#pragma unroll
    for (int i = 0; i < 16; ++i) u16[i] = e[i] + e[16 + i];
#pragma unroll
    for (int i = 0; i < 8; ++i) u16[i] += u16[8 + i];
#pragma unroll
    for (int i = 0; i < 4; ++i) u16[i] += u16[4 + i];
    float rs = (u16[0] + u16[1]) + (u16[2] + u16[3]);
    l_ += rs + __shfl_xor(rs, 32);

    // ---- P fragments directly: pw[t] = pack(e[8t .. 8t+7]) (key perm makes this exact) ----
    bf16x8 pw[4];
#pragma unroll
    for (int t = 0; t < 4; ++t) {
      u32x4 u4;
      u4.x = pkbf(e[8 * t + 0], e[8 * t + 1]);
      u4.y = pkbf(e[8 * t + 2], e[8 * t + 3]);
      u4.z = pkbf(e[8 * t + 4], e[8 * t + 5]);
      u4.w = pkbf(e[8 * t + 6], e[8 * t + 7]);
      pw[t] = __builtin_bit_cast(bf16x8, u4);
    }

    // ---- O^T += V^T·P^T : 2 d-tiles x 4 k-steps; contiguous LDS reads ----
    const char* Vb = VtB + cur * 8192 + qi * 16 + hi * 1024;
    __builtin_amdgcn_s_setprio(1);
#pragma unroll
    for (int t = 0; t < 4; ++t) {
      bf16x8 vf = *(const bf16x8*)(Vb + t * 2048);
      oaccA = __builtin_amdgcn_mfma_f32_32x32x16_bf16(vf, pw[t], oaccA, 0, 0, 0);
    }
#pragma unroll
    for (int t = 0; t < 4; ++t) {
      bf16x8 vf = *(const bf16x8*)(Vb + t * 2048 + 512);
      oaccB = __builtin_amdgcn_mfma_f32_32x32x16_bf16(vf, pw[t], oaccB, 0, 0, 0);
    }
    __builtin_amdgcn_s_setprio(0);
    __syncthreads();
  }
#undef A_STAGE

  // ---- epilogue: lane owns q = qrow; d = m*32 + 8*u + 4*hi + c ----
  const float inv = 1.0f / l_;
  unsigned short* orow = obp + (size_t)qrow * 1024;
#pragma unroll
  for (int u = 0; u < 4; ++u) {
    ushort4 oa, ob;
    oa.x = f2bf(oaccA[4 * u + 0] * inv); oa.y = f2bf(oaccA[4 * u + 1] * inv);
    oa.z = f2bf(oaccA[4 * u + 2] * inv); oa.w = f2bf(oaccA[4 * u + 3] * inv);
    ob.x = f2bf(oaccB[4 * u + 0] * inv); ob.y = f2bf(oaccB[4 * u + 1] * inv);
    ob.z = f2bf(oaccB[4 * u + 2] * inv); ob.w = f2bf(oaccB[4 * u + 3] * inv);
    *(ushort4*)(orow + 8 * u + 4 * hi) = oa;
    *(ushort4*)(orow + 32 + 8 * u + 4 * hi) = ob;
  }
}

// ---------- 4) output GEMM + bias -> fp32 (2-phase dbuf, XCD-swizzled) ----------
__global__ __launch_bounds__(256) void k_gemm_out(const unsigned short* __restrict__ A,
                                                  const unsigned short* __restrict__ Bt,
                                                  const float* __restrict__ bias,
                                                  float* __restrict__ out) {
  __shared__ __align__(16) unsigned short aT[2][128 * 32];
  __shared__ __align__(16) unsigned short bT[2][128 * 32];
  const int tid = threadIdx.x, lane = tid & 63, w = tid >> 6;
  const int wr = w >> 1, wc = w & 1;
  int flat = blockIdx.y * 8 + blockIdx.x;          // nwg = 512, %8==0
  flat = (flat & 7) * 64 + (flat >> 3);
  const int m0 = (flat >> 3) * 128, n0 = (flat & 7) * 128;
  const char* Ab = (const char*)A;
  const char* Bb = (const char*)Bt;
  char* aTb = (char*)aT; char* bTb = (char*)bT;
  f32x4 acc[4][4] = {};

  const int ci0 = w * 2, bo0 = ci0 * 1024 + lane * 16;
  const int srow0 = bo0 >> 6, scol0 = bo0 & 63;
#define G_STAGE(buf, kt)                                                              \
  {                                                                                   \
    _Pragma("unroll")                                                                 \
    for (int j = 0; j < 2; ++j) {                                                     \
      const int row = srow0 + j * 16;                                                 \
      async16(Ab + ((size_t)(m0 + row) * 1024 + (kt) * 32) * 2 + scol0,               \
              aTb + (buf) * 8192 + (ci0 + j) * 1024);                                 \
      async16(Bb + ((size_t)(n0 + row) * 1024 + (kt) * 32) * 2 + scol0,               \
              bTb + (buf) * 8192 + (ci0 + j) * 1024);                                 \
    }                                                                                 \
  }

  G_STAGE(0, 0);
  __syncthreads();
  for (int kt = 0; kt < 32; ++kt) {
    const int cur = kt & 1;
    if (kt + 1 < 32) G_STAGE(cur ^ 1, kt + 1);
    bf16x8 af[4], bfr[4];
#pragma unroll
    for (int mi = 0; mi < 4; ++mi)
      af[mi] = *(const bf16x8*)(aTb + cur * 8192 +
               ((wr * 64 + mi * 16 + (lane & 15)) * 32 + (lane >> 4) * 8) * 2);
#pragma unroll
    for (int ni = 0; ni < 4; ++ni)
      bfr[ni] = *(const bf16x8*)(bTb + cur * 8192 +
               ((wc * 64 + ni * 16 + (lane & 15)) * 32 + (lane >> 4) * 8) * 2);
#pragma unroll
    for (int mi = 0; mi < 4; ++mi)
#pragma unroll
      for (int ni = 0; ni < 4; ++ni)
        acc[mi][ni] = __builtin_amdgcn_mfma_f32_16x16x32_bf16(af[mi], bfr[ni], acc[mi][ni], 0, 0, 0);
    __syncthreads();
  }
#undef G_STAGE
#pragma unroll
  for (int mi = 0; mi < 4; ++mi) {
    const int r0 = m0 + wr * 64 + mi * 16 + (lane >> 4) * 4;
#pragma unroll
    for (int ni = 0; ni < 4; ++ni) {
      const int c = n0 + wc * 64 + ni * 16 + (lane & 15);
      const float bb = bias[c];
#pragma unroll
      for (int r = 0; r < 4; ++r)
        out[(size_t)(r0 + r) * 1024 + c] = acc[mi][ni][r] + bb;
    }
  }
}

// ---------- launcher ----------
extern "C" void kernel_launch(void* const* d_in, const int* in_sizes, int n_in,
                              void* d_out, int out_size, void* d_ws, size_t ws_size,
                              hipStream_t stream) {
  const float* hs   = (const float*)d_in[0];
  const int*   mask = (const int*)d_in[1];
  const float* Wq   = (const float*)d_in[2];
  const float* Wk   = (const float*)d_in[3];
  const float* Wv   = (const float*)d_in[4];
  const float* Wo   = (const float*)d_in[5];
  const float* bo   = (const float*)d_in[6];
  float* out = (float*)d_out;

  const size_t MB = 1024 * 1024;
  char* ws = (char*)d_ws;
  unsigned short* hs_bf  = (unsigned short*)(ws);             // 16 MB
  unsigned short* wt_qkv = (unsigned short*)(ws + 16 * MB);   //  6 MB (q pre-scaled)
  unsigned short* wot    = (unsigned short*)(ws + 22 * MB);   //  2 MB
  unsigned short* qG     = (unsigned short*)(ws + 24 * MB);   // 16 MB [bh][g][t][8]
  unsigned short* kG     = (unsigned short*)(ws + 40 * MB);   // 16 MB [bh][g][perm t][8]
  unsigned short* vG     = (unsigned short*)(ws + 56 * MB);   // 16 MB [bh][t/8][d][t%8]
  unsigned short* o_lin  = (unsigned short*)(ws + 72 * MB);   // 16 MB
  float*          bias_a = (float*)(ws + 88 * MB);            // 32 KB [4][2048]

  k_prep<<<9220, 256, 0, stream>>>(hs, Wq, Wk, Wv, Wo, mask, hs_bf, wt_qkv, wot, bias_a);
  k_gemm_qkv<<<dim3(24, 64), 256, 0, stream>>>(hs_bf, wt_qkv, qG, kG, vG);
  k_attn<<<dim3(16, 64), 256, 0, stream>>>(qG, kG, vG, bias_a, o_lin);
  k_gemm_out<<<dim3(8, 64), 256, 0, stream>>>(o_lin, wot, bo, out);
}